// Round 13
// baseline (4580.187 us; speedup 1.0000x reference)
//
#include <hip/hip_runtime.h>
#include <stdint.h>
#include <stddef.h>

// LSTM 2-layer, B=64,T=1024,D=64,H=256 -> fc(mean_t h)  [MI355X gfx950]
// R13 = R12 with the gx running-pointer stride bug fixed. gemm writes uint2
// per lane: byte strides tloc=131072, gate=32768, wave=4096, j=2048, mt=512,
// lane=8. (R12 had all of these 4x too small -> in-bounds wrong reads,
// absmax 7.6e-2.) Structure unchanged: two-phase step (phase1 MFMAs j=0
// tiles -> j0 repack/act/write -> phase2 MFMAs j=1 overlap j0 VALU -> j1
// act), 16 WGs/layer x 4 batch rows, weights CU-resident (46 frags regs +
// 18 LDS/wave), 512 thr, 2 waves/SIMD, merged gemm launch, fused scans.

#define T_LEN 1024
#define NB    64
#define DIN   64
#define HID   256
#define G4    1024
#define CH    128
#define NCH   (T_LEN/CH)

typedef __attribute__((ext_vector_type(8))) short  bf16x8;
typedef __attribute__((ext_vector_type(4))) float  f32x4;

__device__ __forceinline__ ushort f2b(float x) {      // fp32 -> bf16 RNE
  uint u = __float_as_uint(x);
  uint r = (u + 0x7fffu + ((u >> 16) & 1u)) >> 16;
  return (ushort)r;
}
__device__ __forceinline__ float b2f(uint u16) {      // bf16 -> fp32 exact
  return __uint_as_float(u16 << 16);
}
__device__ __forceinline__ float sigm(float x) {
  float e = __expf(-x);
  return __builtin_amdgcn_rcpf(1.f + e);
}
__device__ __forceinline__ float tanhf_fast(float x) {
  x = fmaxf(-20.f, fminf(20.f, x));                   // exact for tanh, NaN-proof
  float e = __expf(-2.f * x);
  return (1.f - e) * __builtin_amdgcn_rcpf(1.f + e);
}

// ---------------- weight convert (fp32->bf16) + bias sums -----------------
__global__ void convert_weights(const float* __restrict__ Wih0, const float* __restrict__ Whh0,
                                const float* __restrict__ Wih1, const float* __restrict__ Whh1,
                                const float* __restrict__ bih0, const float* __restrict__ bhh0,
                                const float* __restrict__ bih1, const float* __restrict__ bhh1,
                                ushort* __restrict__ Wb, float* __restrict__ bsum)
{
  int i = blockIdx.x * 256 + threadIdx.x;
  const int n0 = G4*DIN, n1 = G4*HID;
  const int total = n0 + 3*n1;                 // 851968
  if (i < total) {
    float v;
    if (i < n0)           v = Wih0[i];
    else if (i < n0+n1)   v = Whh0[i-n0];
    else if (i < n0+2*n1) v = Wih1[i-n0-n1];
    else                  v = Whh1[i-n0-2*n1];
    Wb[i] = f2b(v);
  }
  if (i < G4)        bsum[i] = bih0[i] + bhh0[i];
  else if (i < 2*G4) bsum[i] = bih1[i-G4] + bhh1[i-G4];
}

// ------------- input-projection GEMM body: gx[t] = A_t @ W^T + bias --------
// SRC=0: A = x fp32 [B][T][DIN]  (KDIM=64)
// SRC=1: A = hs0 chunk bf16 [CH][64][HID] (KDIM=256)
// Output gxF bf16 in MFMA-fragment order: [tloc][ct 0..63][mt 0..3][lane][r]
template<int SRC, int KDIM>
__device__ __forceinline__ void gemm_body(
    char* sA, const void* __restrict__ Asrc, const ushort* __restrict__ W,
    const float* __restrict__ bias, ushort* __restrict__ gxF, int t0, int mt0)
{
  const int tid  = threadIdx.x;
  const int wave = tid >> 6, lane = tid & 63;
  const int l15 = lane & 15, lhi = lane >> 4;
  const int tloc = blockIdx.x;
  const int t = t0 + tloc;

  if (SRC == 0) {
    const float* x = (const float*)Asrc;
    int b = tid >> 3, k8 = (tid & 7) * 8;
    const float* xp = x + ((size_t)b * T_LEN + t) * DIN + k8;
    float4 v0 = *(const float4*)xp;
    float4 v1 = *(const float4*)(xp + 4);
    bf16x8 pv;
    pv[0]=(short)f2b(v0.x); pv[1]=(short)f2b(v0.y); pv[2]=(short)f2b(v0.z); pv[3]=(short)f2b(v0.w);
    pv[4]=(short)f2b(v1.x); pv[5]=(short)f2b(v1.y); pv[6]=(short)f2b(v1.z); pv[7]=(short)f2b(v1.w);
    uint bo = (uint)(b * KDIM * 2 + k8 * 2) ^ ((uint)(b & 7) << 4);
    *reinterpret_cast<bf16x8*>(&sA[bo]) = pv;
  } else {
    const ushort* hs = (const ushort*)Asrc;
    int b = tid >> 3, kb = tid & 7;
    #pragma unroll
    for (int j = 0; j < KDIM/64; ++j) {
      int k8 = (kb + j*8) * 8;
      bf16x8 v = *reinterpret_cast<const bf16x8*>(hs + ((size_t)tloc * 64 + b) * KDIM + k8);
      uint bo = (uint)(b * KDIM * 2 + k8 * 2) ^ ((uint)(b & 7) << 4);
      *reinterpret_cast<bf16x8*>(&sA[bo]) = v;
    }
  }
  __syncthreads();

  float bb[8];
  #pragma unroll
  for (int i = 0; i < 8; ++i) bb[i] = bias[(wave*8 + i)*16 + l15];

  f32x4 acc[2][8];
  #pragma unroll
  for (int m = 0; m < 2; ++m)
    #pragma unroll
    for (int i = 0; i < 8; ++i) {
      acc[m][i][0] = bb[i]; acc[m][i][1] = bb[i];
      acc[m][i][2] = bb[i]; acc[m][i][3] = bb[i];
    }

  #pragma unroll
  for (int kc = 0; kc < KDIM/32; ++kc) {
    const int koff = kc*32 + lhi*8;
    bf16x8 wf[8];
    #pragma unroll
    for (int i = 0; i < 8; ++i)
      wf[i] = *reinterpret_cast<const bf16x8*>(W + (size_t)((wave*8 + i)*16 + l15) * KDIM + koff);
    #pragma unroll
    for (int m = 0; m < 2; ++m) {
      const int row = (mt0 + m)*16 + l15;
      const uint bo = (uint)(row * KDIM * 2 + koff * 2) ^ ((uint)(row & 7) << 4);
      bf16x8 a = *reinterpret_cast<const bf16x8*>(&sA[bo]);
      #pragma unroll
      for (int i = 0; i < 8; ++i)
        acc[m][i] = __builtin_amdgcn_mfma_f32_16x16x32_bf16(a, wf[i], acc[m][i], 0, 0, 0);
    }
  }

  #pragma unroll
  for (int m = 0; m < 2; ++m)
    #pragma unroll
    for (int i = 0; i < 8; ++i) {
      const int ct = wave*8 + i;
      uint2 q;
      q.x = (uint)f2b(acc[m][i][0]) | ((uint)f2b(acc[m][i][1]) << 16);
      q.y = (uint)f2b(acc[m][i][2]) | ((uint)f2b(acc[m][i][3]) << 16);
      *reinterpret_cast<uint2*>(gxF + ((size_t)((tloc*64 + ct)*4 + (mt0+m))*64 + lane)*4) = q;
    }
}

// Merged gemm launch: grid (CH, 2..4). y 0,1 = gemm0 (x -> gx0, chunk t0_g0);
// y 2,3 = gemm1 (hs -> gx1, chunk t0_g1). Negative t0 disables a role.
__global__ __launch_bounds__(512) void gemm_both(
    const void* __restrict__ x, const void* __restrict__ hs,
    const ushort* __restrict__ W0, const ushort* __restrict__ W1,
    const float* __restrict__ b0, const float* __restrict__ b1,
    ushort* __restrict__ gx0, ushort* __restrict__ gx1,
    int t0_g0, int t0_g1)
{
  __shared__ __align__(16) char sA[64 * 256 * 2];
  if (blockIdx.y < 2) {
    if (t0_g0 < 0) return;
    gemm_body<0, 64>(sA, x, W0, b0, gx0, t0_g0, blockIdx.y * 2);
  } else {
    if (t0_g1 < 0) return;
    gemm_body<1, 256>(sA, hs, W1, b1, gx1, t0_g1, (blockIdx.y - 2) * 2);
  }
}

// --------------------------- fused recurrent scan --------------------------
// Blocks [0, 16*nL1): layer1 chunk t0_l1 (grp 0..15). Rest: layer0 t0_l0.
// Each grp owns batch rows [grp*4, grp*4+4) in MFMA rows 0..3 (4..15 junk).
// 512 thr, 8 waves, 2 waves/SIMD. Wave w owns units [32w,32w+32) x 4 gates
// = 8 tiles t = gate*2 + j. Frags/wave: 46 regs + 18 LDS.
// Two-phase step: phase1 MFMAs t={0,2,4,6} -> j0 repack/act/write ->
// phase2 MFMAs t={1,3,5,7} (overlaps j0 VALU) -> j1 act. 1 barrier/step.
// gx byte strides (from gemm's uint2-per-lane layout):
//   tloc 131072 | gate 32768 | wave 4096 | j 2048 | mt 512 | gxlane 8.
__global__ __launch_bounds__(512)
__attribute__((amdgpu_waves_per_eu(2, 2)))
void lstm_scan_fused(
    const ushort* __restrict__ gxF0, const ushort* __restrict__ gxF1,
    const ushort* __restrict__ Whh0, const ushort* __restrict__ Whh1,
    ushort* __restrict__ hs_out,     // L0: chunk buffer [CH][64][256] bf16
    float* __restrict__ hsum_out,    // L1: [64][256]
    ushort* __restrict__ hst0, ushort* __restrict__ hst1,
    float* __restrict__ cst0, float* __restrict__ cst1,
    float* __restrict__ hacc_state,  // L1: [16][512][2]
    int t0_l0, int t0_l1, int nL1)
{
  __shared__ __align__(16) char sW[147456];   // [8 waves][18 frags][1024B]
  __shared__ __align__(16) char sH[4096];     // h double buffer, 2 x 2KB

  const int tid = threadIdx.x;
  const int wave = tid >> 6, lane = tid & 63;
  const int l15 = lane & 15, lhi = lane >> 4;
  const int isL0 = (blockIdx.x >= (uint)(16*nL1));
  const int grp  = blockIdx.x - (isL0 ? 16*nL1 : 0);  // 0..15
  const int mt   = grp >> 2;                          // gx M-tile
  const int q4   = grp & 3;                           // row quarter in tile

  const ushort* gxF     = isL0 ? gxF0 : gxF1;
  const ushort* Whh     = isL0 ? Whh0 : Whh1;
  ushort*       h_state = isL0 ? hst0 : hst1;
  float*        c_state = isL0 ? cst0 : cst1;
  const int     t0      = isL0 ? t0_l0 : t0_l1;

  // ---- load weights (once): 46 frags regs + 18 frags LDS per wave ----
  bf16x8 wv[8][6];                             // sparse: 46 live entries
  #pragma unroll
  for (int t = 0; t < 8; ++t) {
    const int g = t >> 1, j = t & 1;
    const ushort* wp = Whh + (size_t)(g*256 + wave*32 + j*16 + l15) * HID;
    #pragma unroll
    for (int kc = 0; kc < 8; ++kc) {
      bf16x8 w = *reinterpret_cast<const bf16x8*>(wp + kc*32 + lhi*8);
      if (kc >= 6 || (kc == 5 && t >= 6)) {
        const int fid = (kc == 6) ? t : (kc == 7) ? (8 + t) : (16 + (t - 6));
        *reinterpret_cast<bf16x8*>(&sW[((wave*18 + fid) << 10) + lane*16]) = w;
      } else {
        wv[t][kc] = w;
      }
    }
  }

  // ---- init / restore h into buffer 0 (2KB = 4 rows x 256 u, swizzled) ----
  if (t0 == 0) {
    if (tid < 512) reinterpret_cast<uint*>(sH)[tid] = 0u;
  } else {
    const uint* src = reinterpret_cast<const uint*>(h_state) + grp*512;
    if (tid < 512) reinterpret_cast<uint*>(sH)[tid] = src[tid];
  }

  float c[2], hacc[2];
  if (t0 == 0) {
    c[0] = c[1] = 0.f; hacc[0] = hacc[1] = 0.f;
  } else {
    const float* cs = c_state + ((size_t)grp*512 + tid)*2;
    c[0] = cs[0]; c[1] = cs[1];
    if (!isL0) {
      const float* ha = hacc_state + ((size_t)grp*512 + tid)*2;
      hacc[0] = ha[0]; hacc[1] = ha[1];
    } else {
      hacc[0] = hacc[1] = 0.f;
    }
  }

  // gx running pointers (byte strides per header comment)
  const int gxlane = (q4 << 4) + l15;
  const char* pgx0 = (const char*)gxF + (size_t)(wave*4096 + mt*512 + gxlane*8);
  const char* pgx1 = pgx0 + 32768;
  const char* pgx2 = pgx0 + 65536;
  const char* pgx3 = pgx0 + 98304;
  #define GXP(g) ((g)==0 ? pgx0 : (g)==1 ? pgx1 : (g)==2 ? pgx2 : pgx3)

  // A-fragment from buffer cb: row = l15&3 (lanes 4-15 duplicate), swizzled
  #define LD_A(cb, kc) (*reinterpret_cast<const bf16x8*>(&sH[(cb)*2048 + \
      (uint)((l15 & 3)*512) + (((uint)((kc)*64 + lhi*16)) ^ ((uint)(l15 & 3) << 5))]))
  // weight fragment (t, kc): regs or LDS, folded at compile time
  #define LD_W(t, kc) (((kc) >= 6 || ((kc) == 5 && (t) >= 6)) ? \
      *reinterpret_cast<const bf16x8*>(&sW[((wave*18 + \
        ((kc) == 6 ? (t) : (kc) == 7 ? (8 + (t)) : (16 + (t) - 6))) << 10) + lane*16]) \
      : wv[t][kc])

  // ---- prefetch gx for step 0 (gxb[t], t = g*2 + j; j at +2048 bytes) ----
  uint2 gxb[8];
  #pragma unroll
  for (int g = 0; g < 4; ++g) {
    gxb[2*g]     = *reinterpret_cast<const uint2*>(GXP(g));
    gxb[2*g + 1] = *reinterpret_cast<const uint2*>(GXP(g) + 2048);
  }

  // hs_out running pointer (L0): byte = tloc*32768 + (grp*4+lhi)*512 + u0*2
  char* hop = (char*)hs_out + (size_t)((grp*4 + lhi)*512 + (wave*32 + l15)*2);

  __syncthreads();

  int cur = 0;
  #pragma unroll 1
  for (int tloc = 0; tloc < CH; ++tloc) {
    // 1. acc init = gx (incl. bias); rows 4-15 are don't-care dups
    f32x4 accA[4], accB[4];
    #pragma unroll
    for (int g = 0; g < 4; ++g) {
      uint2 qa = gxb[2*g], qb = gxb[2*g + 1];
      accA[g][0] = b2f(qa.x & 0xffffu); accA[g][1] = b2f(qa.x >> 16);
      accA[g][2] = b2f(qa.y & 0xffffu); accA[g][3] = b2f(qa.y >> 16);
      accB[g][0] = b2f(qb.x & 0xffffu); accB[g][1] = b2f(qb.x >> 16);
      accB[g][2] = b2f(qb.y & 0xffffu); accB[g][3] = b2f(qb.y >> 16);
    }
    // 2. advance pointers (+tloc stride), issue next step's gx loads
    pgx0 += 131072; pgx1 += 131072; pgx2 += 131072; pgx3 += 131072;
    #pragma unroll
    for (int g = 0; g < 4; ++g) {
      gxb[2*g]     = *reinterpret_cast<const uint2*>(GXP(g));
      gxb[2*g + 1] = *reinterpret_cast<const uint2*>(GXP(g) + 2048);
    }
    // 3. phase 1 MFMAs: tiles {0,2,4,6} (j=0)
    #pragma unroll
    for (int kc = 0; kc < 8; ++kc) {
      bf16x8 a = LD_A(cur, kc);
      #pragma unroll
      for (int g = 0; g < 4; ++g)
        accA[g] = __builtin_amdgcn_mfma_f32_16x16x32_bf16(a, LD_W(2*g, kc), accA[g], 0, 0, 0);
    }
    // 4. j=0 repack + activation + writes (phase-2 MFMAs independent;
    //    scheduler slides them under this VALU block)
    {
      float pa[4];
      #pragma unroll
      for (int g = 0; g < 4; ++g) {
        float v = 0.f;
        #pragma unroll
        for (int r = 0; r < 4; ++r) {
          float sh = __shfl(accA[g][r], l15);
          v = (lhi == r) ? sh : v;
        }
        pa[g] = v;
      }
      float ig = sigm(pa[0]);
      float fg = sigm(pa[1]);
      float gg = tanhf_fast(pa[2]);
      float og = sigm(pa[3]);
      float cn = __builtin_fmaf(fg, c[0], ig * gg);
      c[0] = cn;
      float h = og * tanhf_fast(cn);
      if (!isL0) hacc[0] += h;
      const int u = wave*32 + l15;
      const uint wb = (uint)(lhi*512) + (((uint)(u*2)) ^ ((uint)lhi << 5));
      *reinterpret_cast<ushort*>(&sH[(cur ^ 1)*2048 + wb]) = f2b(h);
      if (isL0) *reinterpret_cast<ushort*>(hop) = f2b(h);
    }
    // 5. phase 2 MFMAs: tiles {1,3,5,7} (j=1)
    #pragma unroll
    for (int kc = 0; kc < 8; ++kc) {
      bf16x8 a = LD_A(cur, kc);
      #pragma unroll
      for (int g = 0; g < 4; ++g)
        accB[g] = __builtin_amdgcn_mfma_f32_16x16x32_bf16(a, LD_W(2*g + 1, kc), accB[g], 0, 0, 0);
    }
    // 6. j=1 repack + activation + writes
    {
      float pa[4];
      #pragma unroll
      for (int g = 0; g < 4; ++g) {
        float v = 0.f;
        #pragma unroll
        for (int r = 0; r < 4; ++r) {
          float sh = __shfl(accB[g][r], l15);
          v = (lhi == r) ? sh : v;
        }
        pa[g] = v;
      }
      float ig = sigm(pa[0]);
      float fg = sigm(pa[1]);
      float gg = tanhf_fast(pa[2]);
      float og = sigm(pa[3]);
      float cn = __builtin_fmaf(fg, c[1], ig * gg);
      c[1] = cn;
      float h = og * tanhf_fast(cn);
      if (!isL0) hacc[1] += h;
      const int u = wave*32 + 16 + l15;
      const uint wb = (uint)(lhi*512) + (((uint)(u*2)) ^ ((uint)lhi << 5));
      *reinterpret_cast<ushort*>(&sH[(cur ^ 1)*2048 + wb]) = f2b(h);
      if (isL0) *reinterpret_cast<ushort*>(hop + 32) = f2b(h);
    }
    if (isL0) hop += 32768;
    __syncthreads();
    cur ^= 1;
  }

  // ---- save state ----
  {
    uint* dst = reinterpret_cast<uint*>(h_state) + grp*512;
    const uint* src = reinterpret_cast<const uint*>(&sH[cur*2048]);
    if (tid < 512) dst[tid] = src[tid];
    float* cs = c_state + ((size_t)grp*512 + tid)*2;
    cs[0] = c[0]; cs[1] = c[1];
    if (!isL0) {
      float* ha = hacc_state + ((size_t)grp*512 + tid)*2;
      ha[0] = hacc[0]; ha[1] = hacc[1];
      #pragma unroll
      for (int j = 0; j < 2; ++j) {
        const int u = wave*32 + j*16 + l15;
        hsum_out[((size_t)grp*4 + lhi)*256 + u] = hacc[j];
      }
    }
  }
  #undef GXP
  #undef LD_A
  #undef LD_W
}

// ------------------------------- final fc ---------------------------------
__global__ void fc_kernel(const float* __restrict__ hsum, const float* __restrict__ Wfc,
                          const float* __restrict__ bfc, float* __restrict__ out)
{
  int tid = threadIdx.x;
  if (tid < 640) {
    int b = tid / 10, o = tid - b*10;
    const float* hp = hsum + b*256;
    const float* wp = Wfc + o*256;
    float s = 0.f;
    #pragma unroll 8
    for (int u = 0; u < 256; ++u) s = __builtin_fmaf(hp[u], wp[u], s);
    out[tid] = s * (1.f/1024.f) + bfc[o];
  }
}

extern "C" void kernel_launch(void* const* d_in, const int* in_sizes, int n_in,
                              void* d_out, int out_size, void* d_ws, size_t ws_size,
                              hipStream_t stream)
{
  const float* x    = (const float*)d_in[0];
  const float* Wih0 = (const float*)d_in[1];
  const float* Whh0 = (const float*)d_in[2];
  const float* bih0 = (const float*)d_in[3];
  const float* bhh0 = (const float*)d_in[4];
  const float* Wih1 = (const float*)d_in[5];
  const float* Whh1 = (const float*)d_in[6];
  const float* bih1 = (const float*)d_in[7];
  const float* bhh1 = (const float*)d_in[8];
  const float* Wfc  = (const float*)d_in[9];
  const float* bfc  = (const float*)d_in[10];
  float* out = (float*)d_out;
  char* ws = (char*)d_ws;

  // ws layout (total ~42.4 MB)
  ushort* Wb    = (ushort*)(ws);                               // 1,703,936 B
  float*  bsum  = (float*)(ws + 1703936);                      // 8 KB
  ushort* gxF0  = (ushort*)(ws + 2097152);                     // 16 MB
  ushort* gxF1  = (ushort*)(ws + 2097152 + 16777216);          // 16 MB
  ushort* hs0cA = (ushort*)(ws + 2097152 + 2*16777216);        // 4 MB
  ushort* hs0cB = (ushort*)(ws + 2097152 + 2*16777216 + 4194304);
  char*   st    = ws + 2097152 + 2*16777216 + 2*4194304;
  float*  hsum  = (float*)(st);                                // 64 KB
  ushort* hst0  = (ushort*)(st + 65536);                       // 32 KB
  ushort* hst1  = (ushort*)(st + 98304);                       // 32 KB
  float*  cst0  = (float*)(st + 131072);                       // 64 KB
  float*  cst1  = (float*)(st + 196608);                       // 64 KB
  float*  hast  = (float*)(st + 262144);                       // 64 KB

  hipLaunchKernelGGL(convert_weights, dim3(3328), dim3(256), 0, stream,
                     Wih0, Whh0, Wih1, Whh1, bih0, bhh0, bih1, bhh1, Wb, bsum);

  const ushort* Whh0b = Wb + 65536;
  const ushort* Wih1b = Wb + 327680;
  const ushort* Whh1b = Wb + 589824;

  ushort* hs0c[2] = { hs0cA, hs0cB };

  // pipeline fill: gemm0 chunk 0, then layer0 scan chunk 0
  hipLaunchKernelGGL(gemm_both, dim3(CH, 2), dim3(512), 0, stream,
                     (const void*)x, (const void*)hs0cA, Wb, Wih1b, bsum, bsum + 1024,
                     gxF0, gxF1, /*t0_g0=*/0, /*t0_g1=*/-1);
  hipLaunchKernelGGL(lstm_scan_fused, dim3(16), dim3(512), 0, stream,
                     gxF0, gxF1, Whh0b, Whh1b, hs0c[0], hsum,
                     hst0, hst1, cst0, cst1, hast, 0, 0, /*nL1=*/0);

  for (int c = 0; c < NCH; ++c) {
    const int nL0 = (c + 1 < NCH) ? 1 : 0;
    // merged: gemm1 chunk c (reads hs0c[c&1]) + gemm0 chunk c+1 (if any)
    hipLaunchKernelGGL(gemm_both, dim3(CH, 4), dim3(512), 0, stream,
                       (const void*)x, (const void*)hs0c[c & 1], Wb, Wih1b,
                       bsum, bsum + 1024, gxF0, gxF1,
                       nL0 ? (c + 1) * CH : -1, c * CH);
    hipLaunchKernelGGL(lstm_scan_fused, dim3(16 + 16*nL0), dim3(512), 0, stream,
                       gxF0, gxF1, Whh0b, Whh1b, hs0c[(c+1) & 1], hsum,
                       hst0, hst1, cst0, cst1, hast, (c+1)*CH, c*CH, /*nL1=*/1);
  }
  hipLaunchKernelGGL(fc_kernel, dim3(1), dim3(640), 0, stream, hsum, Wfc, bfc, out);
}

// Round 14
// 4166.330 us; speedup vs baseline: 1.0993x; 1.0993x over previous
//
#include <hip/hip_runtime.h>
#include <stdint.h>
#include <stddef.h>

// LSTM 2-layer, B=64,T=1024,D=64,H=256 -> fc(mean_t h)  [MI355X gfx950]
// R14: LDS-pipe diet. R11's step was LDS-bound (~4030cy/CU/step): A-reads
// 768 + sW 1728 + __shfl repack = 256 ds_bpermute ~1485 (CDNA __shfl is a
// DS-pipe op!). Fix: NO repack — lane l15 already holds all 4 gates for
// (row r, unit j*16+l15) in acc[t][r]; activate in 16 active lanes (8 elems
// each; wave-wide issue cost is per-inst, VALU has headroom). LDS -> ~2700cy.
// Step core = R11 (kc-major, 8 A-reads, 1 barrier, sH dbuf). Keep R13's
// merged gemm launch + correct-stride running gx pointers (tloc 131072,
// gate 32768, wave 4096, j 2048, mt 512, lane 8). R13's two-phase reverted
// (in-order issue serialized it; 486us vs R11 298us).
// 16 WGs/layer x 4 rows; weights 46 frags regs + 18 LDS per wave; 512 thr.

#define T_LEN 1024
#define NB    64
#define DIN   64
#define HID   256
#define G4    1024
#define CH    128
#define NCH   (T_LEN/CH)

typedef __attribute__((ext_vector_type(8))) short  bf16x8;
typedef __attribute__((ext_vector_type(4))) float  f32x4;

__device__ __forceinline__ ushort f2b(float x) {      // fp32 -> bf16 RNE
  uint u = __float_as_uint(x);
  uint r = (u + 0x7fffu + ((u >> 16) & 1u)) >> 16;
  return (ushort)r;
}
__device__ __forceinline__ float b2f(uint u16) {      // bf16 -> fp32 exact
  return __uint_as_float(u16 << 16);
}
__device__ __forceinline__ float sigm(float x) {
  float e = __expf(-x);
  return __builtin_amdgcn_rcpf(1.f + e);
}
__device__ __forceinline__ float tanhf_fast(float x) {
  x = fmaxf(-20.f, fminf(20.f, x));                   // exact for tanh, NaN-proof
  float e = __expf(-2.f * x);
  return (1.f - e) * __builtin_amdgcn_rcpf(1.f + e);
}

// ---------------- weight convert (fp32->bf16) + bias sums -----------------
__global__ void convert_weights(const float* __restrict__ Wih0, const float* __restrict__ Whh0,
                                const float* __restrict__ Wih1, const float* __restrict__ Whh1,
                                const float* __restrict__ bih0, const float* __restrict__ bhh0,
                                const float* __restrict__ bih1, const float* __restrict__ bhh1,
                                ushort* __restrict__ Wb, float* __restrict__ bsum)
{
  int i = blockIdx.x * 256 + threadIdx.x;
  const int n0 = G4*DIN, n1 = G4*HID;
  const int total = n0 + 3*n1;                 // 851968
  if (i < total) {
    float v;
    if (i < n0)           v = Wih0[i];
    else if (i < n0+n1)   v = Whh0[i-n0];
    else if (i < n0+2*n1) v = Wih1[i-n0-n1];
    else                  v = Whh1[i-n0-2*n1];
    Wb[i] = f2b(v);
  }
  if (i < G4)        bsum[i] = bih0[i] + bhh0[i];
  else if (i < 2*G4) bsum[i] = bih1[i-G4] + bhh1[i-G4];
}

// ------------- input-projection GEMM body: gx[t] = A_t @ W^T + bias --------
// SRC=0: A = x fp32 [B][T][DIN]  (KDIM=64)
// SRC=1: A = hs0 chunk bf16 [CH][64][HID] (KDIM=256)
// Output gxF bf16 in MFMA-fragment order: [tloc][ct 0..63][mt 0..3][lane][r]
template<int SRC, int KDIM>
__device__ __forceinline__ void gemm_body(
    char* sA, const void* __restrict__ Asrc, const ushort* __restrict__ W,
    const float* __restrict__ bias, ushort* __restrict__ gxF, int t0, int mt0)
{
  const int tid  = threadIdx.x;
  const int wave = tid >> 6, lane = tid & 63;
  const int l15 = lane & 15, lhi = lane >> 4;
  const int tloc = blockIdx.x;
  const int t = t0 + tloc;

  if (SRC == 0) {
    const float* x = (const float*)Asrc;
    int b = tid >> 3, k8 = (tid & 7) * 8;
    const float* xp = x + ((size_t)b * T_LEN + t) * DIN + k8;
    float4 v0 = *(const float4*)xp;
    float4 v1 = *(const float4*)(xp + 4);
    bf16x8 pv;
    pv[0]=(short)f2b(v0.x); pv[1]=(short)f2b(v0.y); pv[2]=(short)f2b(v0.z); pv[3]=(short)f2b(v0.w);
    pv[4]=(short)f2b(v1.x); pv[5]=(short)f2b(v1.y); pv[6]=(short)f2b(v1.z); pv[7]=(short)f2b(v1.w);
    uint bo = (uint)(b * KDIM * 2 + k8 * 2) ^ ((uint)(b & 7) << 4);
    *reinterpret_cast<bf16x8*>(&sA[bo]) = pv;
  } else {
    const ushort* hs = (const ushort*)Asrc;
    int b = tid >> 3, kb = tid & 7;
    #pragma unroll
    for (int j = 0; j < KDIM/64; ++j) {
      int k8 = (kb + j*8) * 8;
      bf16x8 v = *reinterpret_cast<const bf16x8*>(hs + ((size_t)tloc * 64 + b) * KDIM + k8);
      uint bo = (uint)(b * KDIM * 2 + k8 * 2) ^ ((uint)(b & 7) << 4);
      *reinterpret_cast<bf16x8*>(&sA[bo]) = v;
    }
  }
  __syncthreads();

  float bb[8];
  #pragma unroll
  for (int i = 0; i < 8; ++i) bb[i] = bias[(wave*8 + i)*16 + l15];

  f32x4 acc[2][8];
  #pragma unroll
  for (int m = 0; m < 2; ++m)
    #pragma unroll
    for (int i = 0; i < 8; ++i) {
      acc[m][i][0] = bb[i]; acc[m][i][1] = bb[i];
      acc[m][i][2] = bb[i]; acc[m][i][3] = bb[i];
    }

  #pragma unroll
  for (int kc = 0; kc < KDIM/32; ++kc) {
    const int koff = kc*32 + lhi*8;
    bf16x8 wf[8];
    #pragma unroll
    for (int i = 0; i < 8; ++i)
      wf[i] = *reinterpret_cast<const bf16x8*>(W + (size_t)((wave*8 + i)*16 + l15) * KDIM + koff);
    #pragma unroll
    for (int m = 0; m < 2; ++m) {
      const int row = (mt0 + m)*16 + l15;
      const uint bo = (uint)(row * KDIM * 2 + koff * 2) ^ ((uint)(row & 7) << 4);
      bf16x8 a = *reinterpret_cast<const bf16x8*>(&sA[bo]);
      #pragma unroll
      for (int i = 0; i < 8; ++i)
        acc[m][i] = __builtin_amdgcn_mfma_f32_16x16x32_bf16(a, wf[i], acc[m][i], 0, 0, 0);
    }
  }

  #pragma unroll
  for (int m = 0; m < 2; ++m)
    #pragma unroll
    for (int i = 0; i < 8; ++i) {
      const int ct = wave*8 + i;
      uint2 q;
      q.x = (uint)f2b(acc[m][i][0]) | ((uint)f2b(acc[m][i][1]) << 16);
      q.y = (uint)f2b(acc[m][i][2]) | ((uint)f2b(acc[m][i][3]) << 16);
      *reinterpret_cast<uint2*>(gxF + ((size_t)((tloc*64 + ct)*4 + (mt0+m))*64 + lane)*4) = q;
    }
}

// Merged gemm launch: grid (CH, 2..4). y 0,1 = gemm0 (x -> gx0, chunk t0_g0);
// y 2,3 = gemm1 (hs -> gx1, chunk t0_g1). Negative t0 disables a role.
__global__ __launch_bounds__(512) void gemm_both(
    const void* __restrict__ x, const void* __restrict__ hs,
    const ushort* __restrict__ W0, const ushort* __restrict__ W1,
    const float* __restrict__ b0, const float* __restrict__ b1,
    ushort* __restrict__ gx0, ushort* __restrict__ gx1,
    int t0_g0, int t0_g1)
{
  __shared__ __align__(16) char sA[64 * 256 * 2];
  if (blockIdx.y < 2) {
    if (t0_g0 < 0) return;
    gemm_body<0, 64>(sA, x, W0, b0, gx0, t0_g0, blockIdx.y * 2);
  } else {
    if (t0_g1 < 0) return;
    gemm_body<1, 256>(sA, hs, W1, b1, gx1, t0_g1, (blockIdx.y - 2) * 2);
  }
}

// --------------------------- fused recurrent scan --------------------------
// Blocks [0, 16*nL1): layer1 chunk t0_l1 (grp 0..15). Rest: layer0 t0_l0.
// Each grp owns batch rows [grp*4, grp*4+4) in MFMA rows 0..3 (4..15 junk).
// 512 thr, 8 waves, 2 waves/SIMD. Wave w owns units [32w,32w+32) x 4 gates
// = 8 tiles t = gate*2 + j. Frags/wave: 46 regs + 18 LDS. kc-major: 8 A
// ds_reads + 64 MFMAs into acc[8]. Activation: NO lane repack — lanes 0-15
// hold all 4 gates for (row r, unit j*16+l15) in acc[t][r]; they activate
// 8 elems each (exec-masked, issue cost unchanged). 1 barrier/step.
__global__ __launch_bounds__(512)
__attribute__((amdgpu_waves_per_eu(2, 2)))
void lstm_scan_fused(
    const ushort* __restrict__ gxF0, const ushort* __restrict__ gxF1,
    const ushort* __restrict__ Whh0, const ushort* __restrict__ Whh1,
    ushort* __restrict__ hs_out,     // L0: chunk buffer [CH][64][256] bf16
    float* __restrict__ hsum_out,    // L1: [64][256]
    ushort* __restrict__ hst0, ushort* __restrict__ hst1,
    float* __restrict__ cst0, float* __restrict__ cst1,
    float* __restrict__ hacc_state,  // L1: [16 grp][8 wave][16 lane][8]
    int t0_l0, int t0_l1, int nL1)
{
  __shared__ __align__(16) char sW[147456];   // [8 waves][18 frags][1024B]
  __shared__ __align__(16) char sH[4096];     // h double buffer, 2 x 2KB

  const int tid = threadIdx.x;
  const int wave = tid >> 6, lane = tid & 63;
  const int l15 = lane & 15, lhi = lane >> 4;
  const int isL0 = (blockIdx.x >= (uint)(16*nL1));
  const int grp  = blockIdx.x - (isL0 ? 16*nL1 : 0);  // 0..15
  const int mt   = grp >> 2;                          // gx M-tile
  const int q4   = grp & 3;                           // row quarter in tile

  const ushort* gxF     = isL0 ? gxF0 : gxF1;
  const ushort* Whh     = isL0 ? Whh0 : Whh1;
  ushort*       h_state = isL0 ? hst0 : hst1;
  float*        c_state = isL0 ? cst0 : cst1;
  const int     t0      = isL0 ? t0_l0 : t0_l1;

  // ---- load weights (once): 46 frags regs + 18 frags LDS per wave ----
  bf16x8 wv[8][6];                             // sparse: 46 live entries
  #pragma unroll
  for (int t = 0; t < 8; ++t) {
    const int g = t >> 1, j = t & 1;
    const ushort* wp = Whh + (size_t)(g*256 + wave*32 + j*16 + l15) * HID;
    #pragma unroll
    for (int kc = 0; kc < 8; ++kc) {
      bf16x8 w = *reinterpret_cast<const bf16x8*>(wp + kc*32 + lhi*8);
      if (kc >= 6 || (kc == 5 && t >= 6)) {
        const int fid = (kc == 6) ? t : (kc == 7) ? (8 + t) : (16 + (t - 6));
        *reinterpret_cast<bf16x8*>(&sW[((wave*18 + fid) << 10) + lane*16]) = w;
      } else {
        wv[t][kc] = w;
      }
    }
  }

  // ---- init / restore h into buffer 0 (2KB = 4 rows x 256 u, swizzled) ----
  if (t0 == 0) {
    if (tid < 512) reinterpret_cast<uint*>(sH)[tid] = 0u;
  } else {
    const uint* src = reinterpret_cast<const uint*>(h_state) + grp*512;
    if (tid < 512) reinterpret_cast<uint*>(sH)[tid] = src[tid];
  }

  // per-lane state (lanes 0-15 of each wave own 8 elems: idx = j*4 + r)
  float c[8], hacc[8];
  const int sidx = ((grp*8 + wave)*16 + l15)*8;    // state base for this lane
  if (t0 == 0) {
    #pragma unroll
    for (int i = 0; i < 8; ++i) { c[i] = 0.f; hacc[i] = 0.f; }
  } else {
    const float* cs = c_state + sidx;
    #pragma unroll
    for (int i = 0; i < 8; ++i) c[i] = (lhi == 0) ? cs[i] : 0.f;
    if (!isL0) {
      const float* ha = hacc_state + sidx;
      #pragma unroll
      for (int i = 0; i < 8; ++i) hacc[i] = (lhi == 0) ? ha[i] : 0.f;
    } else {
      #pragma unroll
      for (int i = 0; i < 8; ++i) hacc[i] = 0.f;
    }
  }

  // gx running pointers: strides tloc 131072 | gate 32768 | wave 4096 |
  // j 2048 | mt 512 | gxlane 8   (gxlane = q4*16 + l15; lhi groups dup)
  const int gxlane = (q4 << 4) + l15;
  const char* pgx0 = (const char*)gxF + (size_t)(wave*4096 + mt*512 + gxlane*8);
  const char* pgx1 = pgx0 + 32768;
  const char* pgx2 = pgx0 + 65536;
  const char* pgx3 = pgx0 + 98304;
  #define GXP(g) ((g)==0 ? pgx0 : (g)==1 ? pgx1 : (g)==2 ? pgx2 : pgx3)

  // A-fragment from buffer cb: row = l15&3 (lanes 4-15 duplicate), swizzled
  #define LD_A(cb, kc) (*reinterpret_cast<const bf16x8*>(&sH[(cb)*2048 + \
      (uint)((l15 & 3)*512) + (((uint)((kc)*64 + lhi*16)) ^ ((uint)(l15 & 3) << 5))]))
  // weight fragment (t, kc): regs or LDS, folded at compile time
  #define LD_W(t, kc) (((kc) >= 6 || ((kc) == 5 && (t) >= 6)) ? \
      *reinterpret_cast<const bf16x8*>(&sW[((wave*18 + \
        ((kc) == 6 ? (t) : (kc) == 7 ? (8 + (t)) : (16 + (t) - 6))) << 10) + lane*16]) \
      : wv[t][kc])

  // ---- prefetch gx for step 0 (gxb[t], t = g*2 + j; j at +2048 bytes) ----
  uint2 gxb[8];
  #pragma unroll
  for (int g = 0; g < 4; ++g) {
    gxb[2*g]     = *reinterpret_cast<const uint2*>(GXP(g));
    gxb[2*g + 1] = *reinterpret_cast<const uint2*>(GXP(g) + 2048);
  }

  // hs_out running pointer (L0, lanes 0-15): byte = tloc*32768 +
  //   (grp*4 + r)*512 + u*2 with u = wave*32 + j*16 + l15
  char* hop = (char*)hs_out + (size_t)(grp*4*512 + (wave*32 + l15)*2);

  __syncthreads();

  int cur = 0;
  #pragma unroll 1
  for (int tloc = 0; tloc < CH; ++tloc) {
    // 1. acc init = gx (incl. bias); rows 4-15 are don't-care dups
    f32x4 acc[8];
    #pragma unroll
    for (int t = 0; t < 8; ++t) {
      uint2 qv = gxb[t];
      acc[t][0] = b2f(qv.x & 0xffffu); acc[t][1] = b2f(qv.x >> 16);
      acc[t][2] = b2f(qv.y & 0xffffu); acc[t][3] = b2f(qv.y >> 16);
    }
    // 2. advance pointers (+tloc stride), issue next step's gx loads
    pgx0 += 131072; pgx1 += 131072; pgx2 += 131072; pgx3 += 131072;
    #pragma unroll
    for (int g = 0; g < 4; ++g) {
      gxb[2*g]     = *reinterpret_cast<const uint2*>(GXP(g));
      gxb[2*g + 1] = *reinterpret_cast<const uint2*>(GXP(g) + 2048);
    }
    // 3. kc-major MFMA block: 8 A-reads, 64 MFMAs (rows 4-15 garbage)
    #pragma unroll
    for (int kc = 0; kc < 8; ++kc) {
      bf16x8 a = LD_A(cur, kc);
      #pragma unroll
      for (int t = 0; t < 8; ++t)
        acc[t] = __builtin_amdgcn_mfma_f32_16x16x32_bf16(a, LD_W(t, kc), acc[t], 0, 0, 0);
    }
    // 4. activation on lanes 0-15 (each owns 8 elems; no cross-lane moves)
    if (lhi == 0) {
      #pragma unroll
      for (int j = 0; j < 2; ++j)
        #pragma unroll
        for (int r = 0; r < 4; ++r) {
          const int idx = j*4 + r;
          float ig = sigm(acc[0 + j][r]);
          float fg = sigm(acc[2 + j][r]);
          float gg = tanhf_fast(acc[4 + j][r]);
          float og = sigm(acc[6 + j][r]);
          float cn = __builtin_fmaf(fg, c[idx], ig * gg);
          c[idx] = cn;
          float h = og * tanhf_fast(cn);
          if (!isL0) hacc[idx] += h;
          const int u = wave*32 + j*16 + l15;
          const uint wb = (uint)(r*512) + (((uint)(u*2)) ^ ((uint)r << 5));
          *reinterpret_cast<ushort*>(&sH[(cur ^ 1)*2048 + wb]) = f2b(h);
          if (isL0)
            *reinterpret_cast<ushort*>(hop + r*512 + j*32) = f2b(h);
        }
    }
    if (isL0) hop += 32768;
    __syncthreads();
    cur ^= 1;
  }

  // ---- save state ----
  {
    uint* dst = reinterpret_cast<uint*>(h_state) + grp*512;
    const uint* src = reinterpret_cast<const uint*>(&sH[cur*2048]);
    if (tid < 512) dst[tid] = src[tid];
    if (lhi == 0) {
      float* cs = c_state + sidx;
      #pragma unroll
      for (int i = 0; i < 8; ++i) cs[i] = c[i];
      if (!isL0) {
        float* ha = hacc_state + sidx;
        #pragma unroll
        for (int i = 0; i < 8; ++i) ha[i] = hacc[i];
        #pragma unroll
        for (int j = 0; j < 2; ++j)
          #pragma unroll
          for (int r = 0; r < 4; ++r) {
            const int u = wave*32 + j*16 + l15;
            hsum_out[((size_t)grp*4 + r)*256 + u] = hacc[j*4 + r];
          }
      }
    }
  }
  #undef GXP
  #undef LD_A
  #undef LD_W
}

// ------------------------------- final fc ---------------------------------
__global__ void fc_kernel(const float* __restrict__ hsum, const float* __restrict__ Wfc,
                          const float* __restrict__ bfc, float* __restrict__ out)
{
  int tid = threadIdx.x;
  if (tid < 640) {
    int b = tid / 10, o = tid - b*10;
    const float* hp = hsum + b*256;
    const float* wp = Wfc + o*256;
    float s = 0.f;
    #pragma unroll 8
    for (int u = 0; u < 256; ++u) s = __builtin_fmaf(hp[u], wp[u], s);
    out[tid] = s * (1.f/1024.f) + bfc[o];
  }
}

extern "C" void kernel_launch(void* const* d_in, const int* in_sizes, int n_in,
                              void* d_out, int out_size, void* d_ws, size_t ws_size,
                              hipStream_t stream)
{
  const float* x    = (const float*)d_in[0];
  const float* Wih0 = (const float*)d_in[1];
  const float* Whh0 = (const float*)d_in[2];
  const float* bih0 = (const float*)d_in[3];
  const float* bhh0 = (const float*)d_in[4];
  const float* Wih1 = (const float*)d_in[5];
  const float* Whh1 = (const float*)d_in[6];
  const float* bih1 = (const float*)d_in[7];
  const float* bhh1 = (const float*)d_in[8];
  const float* Wfc  = (const float*)d_in[9];
  const float* bfc  = (const float*)d_in[10];
  float* out = (float*)d_out;
  char* ws = (char*)d_ws;

  // ws layout (total ~42.4 MB)
  ushort* Wb    = (ushort*)(ws);                               // 1,703,936 B
  float*  bsum  = (float*)(ws + 1703936);                      // 8 KB
  ushort* gxF0  = (ushort*)(ws + 2097152);                     // 16 MB
  ushort* gxF1  = (ushort*)(ws + 2097152 + 16777216);          // 16 MB
  ushort* hs0cA = (ushort*)(ws + 2097152 + 2*16777216);        // 4 MB
  ushort* hs0cB = (ushort*)(ws + 2097152 + 2*16777216 + 4194304);
  char*   st    = ws + 2097152 + 2*16777216 + 2*4194304;
  float*  hsum  = (float*)(st);                                // 64 KB
  ushort* hst0  = (ushort*)(st + 65536);                       // 32 KB
  ushort* hst1  = (ushort*)(st + 98304);                       // 32 KB
  float*  cst0  = (float*)(st + 131072);                       // 64 KB
  float*  cst1  = (float*)(st + 196608);                       // 64 KB
  float*  hast  = (float*)(st + 262144);                       // 64 KB

  hipLaunchKernelGGL(convert_weights, dim3(3328), dim3(256), 0, stream,
                     Wih0, Whh0, Wih1, Whh1, bih0, bhh0, bih1, bhh1, Wb, bsum);

  const ushort* Whh0b = Wb + 65536;
  const ushort* Wih1b = Wb + 327680;
  const ushort* Whh1b = Wb + 589824;

  ushort* hs0c[2] = { hs0cA, hs0cB };

  // pipeline fill: gemm0 chunk 0, then layer0 scan chunk 0
  hipLaunchKernelGGL(gemm_both, dim3(CH, 2), dim3(512), 0, stream,
                     (const void*)x, (const void*)hs0cA, Wb, Wih1b, bsum, bsum + 1024,
                     gxF0, gxF1, /*t0_g0=*/0, /*t0_g1=*/-1);
  hipLaunchKernelGGL(lstm_scan_fused, dim3(16), dim3(512), 0, stream,
                     gxF0, gxF1, Whh0b, Whh1b, hs0c[0], hsum,
                     hst0, hst1, cst0, cst1, hast, 0, 0, /*nL1=*/0);

  for (int c = 0; c < NCH; ++c) {
    const int nL0 = (c + 1 < NCH) ? 1 : 0;
    // merged: gemm1 chunk c (reads hs0c[c&1]) + gemm0 chunk c+1 (if any)
    hipLaunchKernelGGL(gemm_both, dim3(CH, 4), dim3(512), 0, stream,
                       (const void*)x, (const void*)hs0c[c & 1], Wb, Wih1b,
                       bsum, bsum + 1024, gxF0, gxF1,
                       nL0 ? (c + 1) * CH : -1, c * CH);
    hipLaunchKernelGGL(lstm_scan_fused, dim3(16 + 16*nL0), dim3(512), 0, stream,
                       gxF0, gxF1, Whh0b, Whh1b, hs0c[(c+1) & 1], hsum,
                       hst0, hst1, cst0, cst1, hast, (c+1)*CH, c*CH, /*nL1=*/1);
  }
  hipLaunchKernelGGL(fc_kernel, dim3(1), dim3(640), 0, stream, hsum, Wfc, bfc, out);
}

// Round 15
// 2911.921 us; speedup vs baseline: 1.5729x; 1.4308x over previous
//
#include <hip/hip_runtime.h>
#include <stdint.h>
#include <stddef.h>

// LSTM 2-layer, B=64,T=1024,D=64,H=256 -> fc(mean_t h)  [MI355X gfx950]
// R15 = R13 with the two MFMA phases re-merged into R11's single kc-major
// block (8 A-reads/step). R13's phase split serialized (in-order issue) and
// paid +8 A-reads; R14's no-repack quadrupled trans work. R11's balance
// (32-bpermute repack, all-64-lane activation) was the sweet spot. Keep
// R13's merged gemm launch + running-pointer gx/hs_out addressing
// (strides: tloc 131072 | gate 32768 | wave 4096 | j 2048 | mt 512 | ln 8).
// 16 WGs/layer x 4 batch rows; weights CU-resident 46 frags regs + 18 LDS
// per wave; 512 thr, 2 waves/SIMD. Fused: scan0(c+1) || scan1(c).

#define T_LEN 1024
#define NB    64
#define DIN   64
#define HID   256
#define G4    1024
#define CH    128
#define NCH   (T_LEN/CH)

typedef __attribute__((ext_vector_type(8))) short  bf16x8;
typedef __attribute__((ext_vector_type(4))) float  f32x4;

__device__ __forceinline__ ushort f2b(float x) {      // fp32 -> bf16 RNE
  uint u = __float_as_uint(x);
  uint r = (u + 0x7fffu + ((u >> 16) & 1u)) >> 16;
  return (ushort)r;
}
__device__ __forceinline__ float b2f(uint u16) {      // bf16 -> fp32 exact
  return __uint_as_float(u16 << 16);
}
__device__ __forceinline__ float sigm(float x) {
  float e = __expf(-x);
  return __builtin_amdgcn_rcpf(1.f + e);
}
__device__ __forceinline__ float tanhf_fast(float x) {
  x = fmaxf(-20.f, fminf(20.f, x));                   // exact for tanh, NaN-proof
  float e = __expf(-2.f * x);
  return (1.f - e) * __builtin_amdgcn_rcpf(1.f + e);
}

// ---------------- weight convert (fp32->bf16) + bias sums -----------------
__global__ void convert_weights(const float* __restrict__ Wih0, const float* __restrict__ Whh0,
                                const float* __restrict__ Wih1, const float* __restrict__ Whh1,
                                const float* __restrict__ bih0, const float* __restrict__ bhh0,
                                const float* __restrict__ bih1, const float* __restrict__ bhh1,
                                ushort* __restrict__ Wb, float* __restrict__ bsum)
{
  int i = blockIdx.x * 256 + threadIdx.x;
  const int n0 = G4*DIN, n1 = G4*HID;
  const int total = n0 + 3*n1;                 // 851968
  if (i < total) {
    float v;
    if (i < n0)           v = Wih0[i];
    else if (i < n0+n1)   v = Whh0[i-n0];
    else if (i < n0+2*n1) v = Wih1[i-n0-n1];
    else                  v = Whh1[i-n0-2*n1];
    Wb[i] = f2b(v);
  }
  if (i < G4)        bsum[i] = bih0[i] + bhh0[i];
  else if (i < 2*G4) bsum[i] = bih1[i-G4] + bhh1[i-G4];
}

// ------------- input-projection GEMM body: gx[t] = A_t @ W^T + bias --------
// SRC=0: A = x fp32 [B][T][DIN]  (KDIM=64)
// SRC=1: A = hs0 chunk bf16 [CH][64][HID] (KDIM=256)
// Output gxF bf16 in MFMA-fragment order: [tloc][ct 0..63][mt 0..3][lane][r]
template<int SRC, int KDIM>
__device__ __forceinline__ void gemm_body(
    char* sA, const void* __restrict__ Asrc, const ushort* __restrict__ W,
    const float* __restrict__ bias, ushort* __restrict__ gxF, int t0, int mt0)
{
  const int tid  = threadIdx.x;
  const int wave = tid >> 6, lane = tid & 63;
  const int l15 = lane & 15, lhi = lane >> 4;
  const int tloc = blockIdx.x;
  const int t = t0 + tloc;

  if (SRC == 0) {
    const float* x = (const float*)Asrc;
    int b = tid >> 3, k8 = (tid & 7) * 8;
    const float* xp = x + ((size_t)b * T_LEN + t) * DIN + k8;
    float4 v0 = *(const float4*)xp;
    float4 v1 = *(const float4*)(xp + 4);
    bf16x8 pv;
    pv[0]=(short)f2b(v0.x); pv[1]=(short)f2b(v0.y); pv[2]=(short)f2b(v0.z); pv[3]=(short)f2b(v0.w);
    pv[4]=(short)f2b(v1.x); pv[5]=(short)f2b(v1.y); pv[6]=(short)f2b(v1.z); pv[7]=(short)f2b(v1.w);
    uint bo = (uint)(b * KDIM * 2 + k8 * 2) ^ ((uint)(b & 7) << 4);
    *reinterpret_cast<bf16x8*>(&sA[bo]) = pv;
  } else {
    const ushort* hs = (const ushort*)Asrc;
    int b = tid >> 3, kb = tid & 7;
    #pragma unroll
    for (int j = 0; j < KDIM/64; ++j) {
      int k8 = (kb + j*8) * 8;
      bf16x8 v = *reinterpret_cast<const bf16x8*>(hs + ((size_t)tloc * 64 + b) * KDIM + k8);
      uint bo = (uint)(b * KDIM * 2 + k8 * 2) ^ ((uint)(b & 7) << 4);
      *reinterpret_cast<bf16x8*>(&sA[bo]) = v;
    }
  }
  __syncthreads();

  float bb[8];
  #pragma unroll
  for (int i = 0; i < 8; ++i) bb[i] = bias[(wave*8 + i)*16 + l15];

  f32x4 acc[2][8];
  #pragma unroll
  for (int m = 0; m < 2; ++m)
    #pragma unroll
    for (int i = 0; i < 8; ++i) {
      acc[m][i][0] = bb[i]; acc[m][i][1] = bb[i];
      acc[m][i][2] = bb[i]; acc[m][i][3] = bb[i];
    }

  #pragma unroll
  for (int kc = 0; kc < KDIM/32; ++kc) {
    const int koff = kc*32 + lhi*8;
    bf16x8 wf[8];
    #pragma unroll
    for (int i = 0; i < 8; ++i)
      wf[i] = *reinterpret_cast<const bf16x8*>(W + (size_t)((wave*8 + i)*16 + l15) * KDIM + koff);
    #pragma unroll
    for (int m = 0; m < 2; ++m) {
      const int row = (mt0 + m)*16 + l15;
      const uint bo = (uint)(row * KDIM * 2 + koff * 2) ^ ((uint)(row & 7) << 4);
      bf16x8 a = *reinterpret_cast<const bf16x8*>(&sA[bo]);
      #pragma unroll
      for (int i = 0; i < 8; ++i)
        acc[m][i] = __builtin_amdgcn_mfma_f32_16x16x32_bf16(a, wf[i], acc[m][i], 0, 0, 0);
    }
  }

  #pragma unroll
  for (int m = 0; m < 2; ++m)
    #pragma unroll
    for (int i = 0; i < 8; ++i) {
      const int ct = wave*8 + i;
      uint2 q;
      q.x = (uint)f2b(acc[m][i][0]) | ((uint)f2b(acc[m][i][1]) << 16);
      q.y = (uint)f2b(acc[m][i][2]) | ((uint)f2b(acc[m][i][3]) << 16);
      *reinterpret_cast<uint2*>(gxF + ((size_t)((tloc*64 + ct)*4 + (mt0+m))*64 + lane)*4) = q;
    }
}

// Merged gemm launch: grid (CH, 2..4). y 0,1 = gemm0 (x -> gx0, chunk t0_g0);
// y 2,3 = gemm1 (hs -> gx1, chunk t0_g1). Negative t0 disables a role.
__global__ __launch_bounds__(512) void gemm_both(
    const void* __restrict__ x, const void* __restrict__ hs,
    const ushort* __restrict__ W0, const ushort* __restrict__ W1,
    const float* __restrict__ b0, const float* __restrict__ b1,
    ushort* __restrict__ gx0, ushort* __restrict__ gx1,
    int t0_g0, int t0_g1)
{
  __shared__ __align__(16) char sA[64 * 256 * 2];
  if (blockIdx.y < 2) {
    if (t0_g0 < 0) return;
    gemm_body<0, 64>(sA, x, W0, b0, gx0, t0_g0, blockIdx.y * 2);
  } else {
    if (t0_g1 < 0) return;
    gemm_body<1, 256>(sA, hs, W1, b1, gx1, t0_g1, (blockIdx.y - 2) * 2);
  }
}

// --------------------------- fused recurrent scan --------------------------
// Blocks [0, 16*nL1): layer1 chunk t0_l1 (grp 0..15). Rest: layer0 t0_l0.
// Each grp owns batch rows [grp*4, grp*4+4) in MFMA rows 0..3 (4..15 junk).
// 512 thr, 8 waves, 2 waves/SIMD. Wave w owns units [32w,32w+32) x 4 gates
// = 8 tiles t = gate*2 + j. Frags/wave: 46 regs + 18 LDS. Single kc-major
// MFMA block (8 A ds_reads, 64 MFMAs into accA/accB), then j0 and j1
// repack (shfl-broadcast from lanes 0-15) + activation. 1 barrier/step.
__global__ __launch_bounds__(512)
__attribute__((amdgpu_waves_per_eu(2, 2)))
void lstm_scan_fused(
    const ushort* __restrict__ gxF0, const ushort* __restrict__ gxF1,
    const ushort* __restrict__ Whh0, const ushort* __restrict__ Whh1,
    ushort* __restrict__ hs_out,     // L0: chunk buffer [CH][64][256] bf16
    float* __restrict__ hsum_out,    // L1: [64][256]
    ushort* __restrict__ hst0, ushort* __restrict__ hst1,
    float* __restrict__ cst0, float* __restrict__ cst1,
    float* __restrict__ hacc_state,  // L1: [16][512][2]
    int t0_l0, int t0_l1, int nL1)
{
  __shared__ __align__(16) char sW[147456];   // [8 waves][18 frags][1024B]
  __shared__ __align__(16) char sH[4096];     // h double buffer, 2 x 2KB

  const int tid = threadIdx.x;
  const int wave = tid >> 6, lane = tid & 63;
  const int l15 = lane & 15, lhi = lane >> 4;
  const int isL0 = (blockIdx.x >= (uint)(16*nL1));
  const int grp  = blockIdx.x - (isL0 ? 16*nL1 : 0);  // 0..15
  const int mt   = grp >> 2;                          // gx M-tile
  const int q4   = grp & 3;                           // row quarter in tile

  const ushort* gxF     = isL0 ? gxF0 : gxF1;
  const ushort* Whh     = isL0 ? Whh0 : Whh1;
  ushort*       h_state = isL0 ? hst0 : hst1;
  float*        c_state = isL0 ? cst0 : cst1;
  const int     t0      = isL0 ? t0_l0 : t0_l1;

  // ---- load weights (once): 46 frags regs + 18 frags LDS per wave ----
  bf16x8 wv[8][6];                             // sparse: 46 live entries
  #pragma unroll
  for (int t = 0; t < 8; ++t) {
    const int g = t >> 1, j = t & 1;
    const ushort* wp = Whh + (size_t)(g*256 + wave*32 + j*16 + l15) * HID;
    #pragma unroll
    for (int kc = 0; kc < 8; ++kc) {
      bf16x8 w = *reinterpret_cast<const bf16x8*>(wp + kc*32 + lhi*8);
      if (kc >= 6 || (kc == 5 && t >= 6)) {
        const int fid = (kc == 6) ? t : (kc == 7) ? (8 + t) : (16 + (t - 6));
        *reinterpret_cast<bf16x8*>(&sW[((wave*18 + fid) << 10) + lane*16]) = w;
      } else {
        wv[t][kc] = w;
      }
    }
  }

  // ---- init / restore h into buffer 0 (2KB = 4 rows x 256 u, swizzled) ----
  if (t0 == 0) {
    if (tid < 512) reinterpret_cast<uint*>(sH)[tid] = 0u;
  } else {
    const uint* src = reinterpret_cast<const uint*>(h_state) + grp*512;
    if (tid < 512) reinterpret_cast<uint*>(sH)[tid] = src[tid];
  }

  float c[2], hacc[2];
  if (t0 == 0) {
    c[0] = c[1] = 0.f; hacc[0] = hacc[1] = 0.f;
  } else {
    const float* cs = c_state + ((size_t)grp*512 + tid)*2;
    c[0] = cs[0]; c[1] = cs[1];
    if (!isL0) {
      const float* ha = hacc_state + ((size_t)grp*512 + tid)*2;
      hacc[0] = ha[0]; hacc[1] = ha[1];
    } else {
      hacc[0] = hacc[1] = 0.f;
    }
  }

  // gx running pointers (byte strides per header comment)
  const int gxlane = (q4 << 4) + l15;
  const char* pgx0 = (const char*)gxF + (size_t)(wave*4096 + mt*512 + gxlane*8);
  const char* pgx1 = pgx0 + 32768;
  const char* pgx2 = pgx0 + 65536;
  const char* pgx3 = pgx0 + 98304;
  #define GXP(g) ((g)==0 ? pgx0 : (g)==1 ? pgx1 : (g)==2 ? pgx2 : pgx3)

  // A-fragment from buffer cb: row = l15&3 (lanes 4-15 duplicate), swizzled
  #define LD_A(cb, kc) (*reinterpret_cast<const bf16x8*>(&sH[(cb)*2048 + \
      (uint)((l15 & 3)*512) + (((uint)((kc)*64 + lhi*16)) ^ ((uint)(l15 & 3) << 5))]))
  // weight fragment (t, kc): regs or LDS, folded at compile time
  #define LD_W(t, kc) (((kc) >= 6 || ((kc) == 5 && (t) >= 6)) ? \
      *reinterpret_cast<const bf16x8*>(&sW[((wave*18 + \
        ((kc) == 6 ? (t) : (kc) == 7 ? (8 + (t)) : (16 + (t) - 6))) << 10) + lane*16]) \
      : wv[t][kc])

  // ---- prefetch gx for step 0 (gxb[t], t = g*2 + j; j at +2048 bytes) ----
  uint2 gxb[8];
  #pragma unroll
  for (int g = 0; g < 4; ++g) {
    gxb[2*g]     = *reinterpret_cast<const uint2*>(GXP(g));
    gxb[2*g + 1] = *reinterpret_cast<const uint2*>(GXP(g) + 2048);
  }

  // hs_out running pointer (L0): byte = tloc*32768 + (grp*4+lhi)*512 + u0*2
  char* hop = (char*)hs_out + (size_t)((grp*4 + lhi)*512 + (wave*32 + l15)*2);

  __syncthreads();

  int cur = 0;
  #pragma unroll 1
  for (int tloc = 0; tloc < CH; ++tloc) {
    // 1. acc init = gx (incl. bias); rows 4-15 are don't-care dups
    f32x4 accA[4], accB[4];
    #pragma unroll
    for (int g = 0; g < 4; ++g) {
      uint2 qa = gxb[2*g], qb = gxb[2*g + 1];
      accA[g][0] = b2f(qa.x & 0xffffu); accA[g][1] = b2f(qa.x >> 16);
      accA[g][2] = b2f(qa.y & 0xffffu); accA[g][3] = b2f(qa.y >> 16);
      accB[g][0] = b2f(qb.x & 0xffffu); accB[g][1] = b2f(qb.x >> 16);
      accB[g][2] = b2f(qb.y & 0xffffu); accB[g][3] = b2f(qb.y >> 16);
    }
    // 2. advance pointers (+tloc stride), issue next step's gx loads
    pgx0 += 131072; pgx1 += 131072; pgx2 += 131072; pgx3 += 131072;
    #pragma unroll
    for (int g = 0; g < 4; ++g) {
      gxb[2*g]     = *reinterpret_cast<const uint2*>(GXP(g));
      gxb[2*g + 1] = *reinterpret_cast<const uint2*>(GXP(g) + 2048);
    }
    // 3. single kc-major MFMA block: 8 A-reads, 64 MFMAs (rows 4-15 junk)
    #pragma unroll
    for (int kc = 0; kc < 8; ++kc) {
      bf16x8 a = LD_A(cur, kc);
      #pragma unroll
      for (int g = 0; g < 4; ++g) {
        accA[g] = __builtin_amdgcn_mfma_f32_16x16x32_bf16(a, LD_W(2*g,     kc), accA[g], 0, 0, 0);
        accB[g] = __builtin_amdgcn_mfma_f32_16x16x32_bf16(a, LD_W(2*g + 1, kc), accB[g], 0, 0, 0);
      }
    }
    // 4. j=0 repack + activation + writes
    {
      float pa[4];
      #pragma unroll
      for (int g = 0; g < 4; ++g) {
        float v = 0.f;
        #pragma unroll
        for (int r = 0; r < 4; ++r) {
          float sh = __shfl(accA[g][r], l15);
          v = (lhi == r) ? sh : v;
        }
        pa[g] = v;
      }
      float ig = sigm(pa[0]);
      float fg = sigm(pa[1]);
      float gg = tanhf_fast(pa[2]);
      float og = sigm(pa[3]);
      float cn = __builtin_fmaf(fg, c[0], ig * gg);
      c[0] = cn;
      float h = og * tanhf_fast(cn);
      if (!isL0) hacc[0] += h;
      const int u = wave*32 + l15;
      const uint wb = (uint)(lhi*512) + (((uint)(u*2)) ^ ((uint)lhi << 5));
      *reinterpret_cast<ushort*>(&sH[(cur ^ 1)*2048 + wb]) = f2b(h);
      if (isL0) *reinterpret_cast<ushort*>(hop) = f2b(h);
    }
    // 5. j=1 repack + activation + writes
    {
      float pa[4];
      #pragma unroll
      for (int g = 0; g < 4; ++g) {
        float v = 0.f;
        #pragma unroll
        for (int r = 0; r < 4; ++r) {
          float sh = __shfl(accB[g][r], l15);
          v = (lhi == r) ? sh : v;
        }
        pa[g] = v;
      }
      float ig = sigm(pa[0]);
      float fg = sigm(pa[1]);
      float gg = tanhf_fast(pa[2]);
      float og = sigm(pa[3]);
      float cn = __builtin_fmaf(fg, c[1], ig * gg);
      c[1] = cn;
      float h = og * tanhf_fast(cn);
      if (!isL0) hacc[1] += h;
      const int u = wave*32 + 16 + l15;
      const uint wb = (uint)(lhi*512) + (((uint)(u*2)) ^ ((uint)lhi << 5));
      *reinterpret_cast<ushort*>(&sH[(cur ^ 1)*2048 + wb]) = f2b(h);
      if (isL0) *reinterpret_cast<ushort*>(hop + 32) = f2b(h);
    }
    if (isL0) hop += 32768;
    __syncthreads();
    cur ^= 1;
  }

  // ---- save state ----
  {
    uint* dst = reinterpret_cast<uint*>(h_state) + grp*512;
    const uint* src = reinterpret_cast<const uint*>(&sH[cur*2048]);
    if (tid < 512) dst[tid] = src[tid];
    float* cs = c_state + ((size_t)grp*512 + tid)*2;
    cs[0] = c[0]; cs[1] = c[1];
    if (!isL0) {
      float* ha = hacc_state + ((size_t)grp*512 + tid)*2;
      ha[0] = hacc[0]; ha[1] = hacc[1];
      #pragma unroll
      for (int j = 0; j < 2; ++j) {
        const int u = wave*32 + j*16 + l15;
        hsum_out[((size_t)grp*4 + lhi)*256 + u] = hacc[j];
      }
    }
  }
  #undef GXP
  #undef LD_A
  #undef LD_W
}

// ------------------------------- final fc ---------------------------------
__global__ void fc_kernel(const float* __restrict__ hsum, const float* __restrict__ Wfc,
                          const float* __restrict__ bfc, float* __restrict__ out)
{
  int tid = threadIdx.x;
  if (tid < 640) {
    int b = tid / 10, o = tid - b*10;
    const float* hp = hsum + b*256;
    const float* wp = Wfc + o*256;
    float s = 0.f;
    #pragma unroll 8
    for (int u = 0; u < 256; ++u) s = __builtin_fmaf(hp[u], wp[u], s);
    out[tid] = s * (1.f/1024.f) + bfc[o];
  }
}

extern "C" void kernel_launch(void* const* d_in, const int* in_sizes, int n_in,
                              void* d_out, int out_size, void* d_ws, size_t ws_size,
                              hipStream_t stream)
{
  const float* x    = (const float*)d_in[0];
  const float* Wih0 = (const float*)d_in[1];
  const float* Whh0 = (const float*)d_in[2];
  const float* bih0 = (const float*)d_in[3];
  const float* bhh0 = (const float*)d_in[4];
  const float* Wih1 = (const float*)d_in[5];
  const float* Whh1 = (const float*)d_in[6];
  const float* bih1 = (const float*)d_in[7];
  const float* bhh1 = (const float*)d_in[8];
  const float* Wfc  = (const float*)d_in[9];
  const float* bfc  = (const float*)d_in[10];
  float* out = (float*)d_out;
  char* ws = (char*)d_ws;

  // ws layout (total ~42.4 MB)
  ushort* Wb    = (ushort*)(ws);                               // 1,703,936 B
  float*  bsum  = (float*)(ws + 1703936);                      // 8 KB
  ushort* gxF0  = (ushort*)(ws + 2097152);                     // 16 MB
  ushort* gxF1  = (ushort*)(ws + 2097152 + 16777216);          // 16 MB
  ushort* hs0cA = (ushort*)(ws + 2097152 + 2*16777216);        // 4 MB
  ushort* hs0cB = (ushort*)(ws + 2097152 + 2*16777216 + 4194304);
  char*   st    = ws + 2097152 + 2*16777216 + 2*4194304;
  float*  hsum  = (float*)(st);                                // 64 KB
  ushort* hst0  = (ushort*)(st + 65536);                       // 32 KB
  ushort* hst1  = (ushort*)(st + 98304);                       // 32 KB
  float*  cst0  = (float*)(st + 131072);                       // 64 KB
  float*  cst1  = (float*)(st + 196608);                       // 64 KB
  float*  hast  = (float*)(st + 262144);                       // 64 KB

  hipLaunchKernelGGL(convert_weights, dim3(3328), dim3(256), 0, stream,
                     Wih0, Whh0, Wih1, Whh1, bih0, bhh0, bih1, bhh1, Wb, bsum);

  const ushort* Whh0b = Wb + 65536;
  const ushort* Wih1b = Wb + 327680;
  const ushort* Whh1b = Wb + 589824;

  ushort* hs0c[2] = { hs0cA, hs0cB };

  // pipeline fill: gemm0 chunk 0, then layer0 scan chunk 0
  hipLaunchKernelGGL(gemm_both, dim3(CH, 2), dim3(512), 0, stream,
                     (const void*)x, (const void*)hs0cA, Wb, Wih1b, bsum, bsum + 1024,
                     gxF0, gxF1, /*t0_g0=*/0, /*t0_g1=*/-1);
  hipLaunchKernelGGL(lstm_scan_fused, dim3(16), dim3(512), 0, stream,
                     gxF0, gxF1, Whh0b, Whh1b, hs0c[0], hsum,
                     hst0, hst1, cst0, cst1, hast, 0, 0, /*nL1=*/0);

  for (int c = 0; c < NCH; ++c) {
    const int nL0 = (c + 1 < NCH) ? 1 : 0;
    // merged: gemm1 chunk c (reads hs0c[c&1]) + gemm0 chunk c+1 (if any)
    hipLaunchKernelGGL(gemm_both, dim3(CH, 4), dim3(512), 0, stream,
                       (const void*)x, (const void*)hs0c[c & 1], Wb, Wih1b,
                       bsum, bsum + 1024, gxF0, gxF1,
                       nL0 ? (c + 1) * CH : -1, c * CH);
    hipLaunchKernelGGL(lstm_scan_fused, dim3(16 + 16*nL0), dim3(512), 0, stream,
                       gxF0, gxF1, Whh0b, Whh1b, hs0c[(c+1) & 1], hsum,
                       hst0, hst1, cst0, cst1, hast, (c+1)*CH, c*CH, /*nL1=*/1);
  }
  hipLaunchKernelGGL(fc_kernel, dim3(1), dim3(640), 0, stream, hsum, Wfc, bfc, out);
}

// Round 16
// 2394.622 us; speedup vs baseline: 1.9127x; 1.2160x over previous
//
#include <hip/hip_runtime.h>
#include <stdint.h>
#include <stddef.h>

// LSTM 2-layer, B=64,T=1024,D=64,H=256 -> fc(mean_t h)  [MI355X gfx950]
// R16: repack ELIMINATED via MFMA row placement. C/D row = lhi*4 + reg, so
// placing real batch row b at A-rows 4b..4b+3 (LD_A row = l15>>2; dups
// unused) puts element (row lhi, unit l15) in lane (lhi,l15) reg 0 — the
// R11 work split with zero cross-lane moves (was 256 ds_bpermute/step/CU
// ~1485cy of the ~4000cy LDS pipe). gx init selects reg lhi from the uint2
// (4 ops) instead of unpacking 4. Bit-identical numerics.
// Else = R15: kc-major 64-MFMA block, 8 A-reads/step, sH dbuf 1 barrier,
// 16 WGs/layer x 4 rows, weights 46 frags regs + 18 LDS per wave, 512 thr,
// 2 waves/SIMD, merged gemm launch, fused scan0(c+1) || scan1(c).

#define T_LEN 1024
#define NB    64
#define DIN   64
#define HID   256
#define G4    1024
#define CH    128
#define NCH   (T_LEN/CH)

typedef __attribute__((ext_vector_type(8))) short  bf16x8;
typedef __attribute__((ext_vector_type(4))) float  f32x4;

__device__ __forceinline__ ushort f2b(float x) {      // fp32 -> bf16 RNE
  uint u = __float_as_uint(x);
  uint r = (u + 0x7fffu + ((u >> 16) & 1u)) >> 16;
  return (ushort)r;
}
__device__ __forceinline__ float b2f(uint u16) {      // bf16 -> fp32 exact
  return __uint_as_float(u16 << 16);
}
__device__ __forceinline__ float sigm(float x) {
  float e = __expf(-x);
  return __builtin_amdgcn_rcpf(1.f + e);
}
__device__ __forceinline__ float tanhf_fast(float x) {
  x = fmaxf(-20.f, fminf(20.f, x));                   // exact for tanh, NaN-proof
  float e = __expf(-2.f * x);
  return (1.f - e) * __builtin_amdgcn_rcpf(1.f + e);
}
// select bf16 reg `sel` (0..3) from a gx uint2, as fp32
__device__ __forceinline__ float sel4(uint2 qv, int sel) {
  uint w = (sel & 2) ? qv.y : qv.x;
  uint v = (sel & 1) ? (w & 0xffff0000u) : (w << 16);
  return __uint_as_float(v);
}

// ---------------- weight convert (fp32->bf16) + bias sums -----------------
__global__ void convert_weights(const float* __restrict__ Wih0, const float* __restrict__ Whh0,
                                const float* __restrict__ Wih1, const float* __restrict__ Whh1,
                                const float* __restrict__ bih0, const float* __restrict__ bhh0,
                                const float* __restrict__ bih1, const float* __restrict__ bhh1,
                                ushort* __restrict__ Wb, float* __restrict__ bsum)
{
  int i = blockIdx.x * 256 + threadIdx.x;
  const int n0 = G4*DIN, n1 = G4*HID;
  const int total = n0 + 3*n1;                 // 851968
  if (i < total) {
    float v;
    if (i < n0)           v = Wih0[i];
    else if (i < n0+n1)   v = Whh0[i-n0];
    else if (i < n0+2*n1) v = Wih1[i-n0-n1];
    else                  v = Whh1[i-n0-2*n1];
    Wb[i] = f2b(v);
  }
  if (i < G4)        bsum[i] = bih0[i] + bhh0[i];
  else if (i < 2*G4) bsum[i] = bih1[i-G4] + bhh1[i-G4];
}

// ------------- input-projection GEMM body: gx[t] = A_t @ W^T + bias --------
// SRC=0: A = x fp32 [B][T][DIN]  (KDIM=64)
// SRC=1: A = hs0 chunk bf16 [CH][64][HID] (KDIM=256)
// Output gxF bf16 in MFMA-fragment order: [tloc][ct 0..63][mt 0..3][lane][r]
template<int SRC, int KDIM>
__device__ __forceinline__ void gemm_body(
    char* sA, const void* __restrict__ Asrc, const ushort* __restrict__ W,
    const float* __restrict__ bias, ushort* __restrict__ gxF, int t0, int mt0)
{
  const int tid  = threadIdx.x;
  const int wave = tid >> 6, lane = tid & 63;
  const int l15 = lane & 15, lhi = lane >> 4;
  const int tloc = blockIdx.x;
  const int t = t0 + tloc;

  if (SRC == 0) {
    const float* x = (const float*)Asrc;
    int b = tid >> 3, k8 = (tid & 7) * 8;
    const float* xp = x + ((size_t)b * T_LEN + t) * DIN + k8;
    float4 v0 = *(const float4*)xp;
    float4 v1 = *(const float4*)(xp + 4);
    bf16x8 pv;
    pv[0]=(short)f2b(v0.x); pv[1]=(short)f2b(v0.y); pv[2]=(short)f2b(v0.z); pv[3]=(short)f2b(v0.w);
    pv[4]=(short)f2b(v1.x); pv[5]=(short)f2b(v1.y); pv[6]=(short)f2b(v1.z); pv[7]=(short)f2b(v1.w);
    uint bo = (uint)(b * KDIM * 2 + k8 * 2) ^ ((uint)(b & 7) << 4);
    *reinterpret_cast<bf16x8*>(&sA[bo]) = pv;
  } else {
    const ushort* hs = (const ushort*)Asrc;
    int b = tid >> 3, kb = tid & 7;
    #pragma unroll
    for (int j = 0; j < KDIM/64; ++j) {
      int k8 = (kb + j*8) * 8;
      bf16x8 v = *reinterpret_cast<const bf16x8*>(hs + ((size_t)tloc * 64 + b) * KDIM + k8);
      uint bo = (uint)(b * KDIM * 2 + k8 * 2) ^ ((uint)(b & 7) << 4);
      *reinterpret_cast<bf16x8*>(&sA[bo]) = v;
    }
  }
  __syncthreads();

  float bb[8];
  #pragma unroll
  for (int i = 0; i < 8; ++i) bb[i] = bias[(wave*8 + i)*16 + l15];

  f32x4 acc[2][8];
  #pragma unroll
  for (int m = 0; m < 2; ++m)
    #pragma unroll
    for (int i = 0; i < 8; ++i) {
      acc[m][i][0] = bb[i]; acc[m][i][1] = bb[i];
      acc[m][i][2] = bb[i]; acc[m][i][3] = bb[i];
    }

  #pragma unroll
  for (int kc = 0; kc < KDIM/32; ++kc) {
    const int koff = kc*32 + lhi*8;
    bf16x8 wf[8];
    #pragma unroll
    for (int i = 0; i < 8; ++i)
      wf[i] = *reinterpret_cast<const bf16x8*>(W + (size_t)((wave*8 + i)*16 + l15) * KDIM + koff);
    #pragma unroll
    for (int m = 0; m < 2; ++m) {
      const int row = (mt0 + m)*16 + l15;
      const uint bo = (uint)(row * KDIM * 2 + koff * 2) ^ ((uint)(row & 7) << 4);
      bf16x8 a = *reinterpret_cast<const bf16x8*>(&sA[bo]);
      #pragma unroll
      for (int i = 0; i < 8; ++i)
        acc[m][i] = __builtin_amdgcn_mfma_f32_16x16x32_bf16(a, wf[i], acc[m][i], 0, 0, 0);
    }
  }

  #pragma unroll
  for (int m = 0; m < 2; ++m)
    #pragma unroll
    for (int i = 0; i < 8; ++i) {
      const int ct = wave*8 + i;
      uint2 q;
      q.x = (uint)f2b(acc[m][i][0]) | ((uint)f2b(acc[m][i][1]) << 16);
      q.y = (uint)f2b(acc[m][i][2]) | ((uint)f2b(acc[m][i][3]) << 16);
      *reinterpret_cast<uint2*>(gxF + ((size_t)((tloc*64 + ct)*4 + (mt0+m))*64 + lane)*4) = q;
    }
}

// Merged gemm launch: grid (CH, 2..4). y 0,1 = gemm0 (x -> gx0, chunk t0_g0);
// y 2,3 = gemm1 (hs -> gx1, chunk t0_g1). Negative t0 disables a role.
__global__ __launch_bounds__(512) void gemm_both(
    const void* __restrict__ x, const void* __restrict__ hs,
    const ushort* __restrict__ W0, const ushort* __restrict__ W1,
    const float* __restrict__ b0, const float* __restrict__ b1,
    ushort* __restrict__ gx0, ushort* __restrict__ gx1,
    int t0_g0, int t0_g1)
{
  __shared__ __align__(16) char sA[64 * 256 * 2];
  if (blockIdx.y < 2) {
    if (t0_g0 < 0) return;
    gemm_body<0, 64>(sA, x, W0, b0, gx0, t0_g0, blockIdx.y * 2);
  } else {
    if (t0_g1 < 0) return;
    gemm_body<1, 256>(sA, hs, W1, b1, gx1, t0_g1, (blockIdx.y - 2) * 2);
  }
}

// --------------------------- fused recurrent scan --------------------------
// Blocks [0, 16*nL1): layer1 chunk t0_l1 (grp 0..15). Rest: layer0 t0_l0.
// Each grp owns batch rows [grp*4, grp*4+4), placed at MFMA A-rows 4b..4b+3
// (LD_A row = l15>>2). C/D row = lhi*4 + reg, so lane (lhi,l15) reg 0 holds
// element (row lhi, unit tile_col + l15) directly — no cross-lane repack.
// 512 thr, 8 waves, 2 waves/SIMD. Wave w owns units [32w,32w+32) x 4 gates
// = 8 tiles t = gate*2 + j. Frags/wave: 46 regs + 18 LDS. kc-major single
// MFMA block (8 A ds_reads, 64 MFMAs), then j0/j1 activation. 1 barrier/step.
__global__ __launch_bounds__(512)
__attribute__((amdgpu_waves_per_eu(2, 2)))
void lstm_scan_fused(
    const ushort* __restrict__ gxF0, const ushort* __restrict__ gxF1,
    const ushort* __restrict__ Whh0, const ushort* __restrict__ Whh1,
    ushort* __restrict__ hs_out,     // L0: chunk buffer [CH][64][256] bf16
    float* __restrict__ hsum_out,    // L1: [64][256]
    ushort* __restrict__ hst0, ushort* __restrict__ hst1,
    float* __restrict__ cst0, float* __restrict__ cst1,
    float* __restrict__ hacc_state,  // L1: [16][512][2]
    int t0_l0, int t0_l1, int nL1)
{
  __shared__ __align__(16) char sW[147456];   // [8 waves][18 frags][1024B]
  __shared__ __align__(16) char sH[4096];     // h double buffer, 2 x 2KB

  const int tid = threadIdx.x;
  const int wave = tid >> 6, lane = tid & 63;
  const int l15 = lane & 15, lhi = lane >> 4;
  const int isL0 = (blockIdx.x >= (uint)(16*nL1));
  const int grp  = blockIdx.x - (isL0 ? 16*nL1 : 0);  // 0..15
  const int mt   = grp >> 2;                          // gx M-tile
  const int q4   = grp & 3;                           // row quarter in tile

  const ushort* gxF     = isL0 ? gxF0 : gxF1;
  const ushort* Whh     = isL0 ? Whh0 : Whh1;
  ushort*       h_state = isL0 ? hst0 : hst1;
  float*        c_state = isL0 ? cst0 : cst1;
  const int     t0      = isL0 ? t0_l0 : t0_l1;

  // ---- load weights (once): 46 frags regs + 18 frags LDS per wave ----
  bf16x8 wv[8][6];                             // sparse: 46 live entries
  #pragma unroll
  for (int t = 0; t < 8; ++t) {
    const int g = t >> 1, j = t & 1;
    const ushort* wp = Whh + (size_t)(g*256 + wave*32 + j*16 + l15) * HID;
    #pragma unroll
    for (int kc = 0; kc < 8; ++kc) {
      bf16x8 w = *reinterpret_cast<const bf16x8*>(wp + kc*32 + lhi*8);
      if (kc >= 6 || (kc == 5 && t >= 6)) {
        const int fid = (kc == 6) ? t : (kc == 7) ? (8 + t) : (16 + (t - 6));
        *reinterpret_cast<bf16x8*>(&sW[((wave*18 + fid) << 10) + lane*16]) = w;
      } else {
        wv[t][kc] = w;
      }
    }
  }

  // ---- init / restore h into buffer 0 (2KB = 4 rows x 256 u, swizzled) ----
  if (t0 == 0) {
    if (tid < 512) reinterpret_cast<uint*>(sH)[tid] = 0u;
  } else {
    const uint* src = reinterpret_cast<const uint*>(h_state) + grp*512;
    if (tid < 512) reinterpret_cast<uint*>(sH)[tid] = src[tid];
  }

  float c[2], hacc[2];
  if (t0 == 0) {
    c[0] = c[1] = 0.f; hacc[0] = hacc[1] = 0.f;
  } else {
    const float* cs = c_state + ((size_t)grp*512 + tid)*2;
    c[0] = cs[0]; c[1] = cs[1];
    if (!isL0) {
      const float* ha = hacc_state + ((size_t)grp*512 + tid)*2;
      hacc[0] = ha[0]; hacc[1] = ha[1];
    } else {
      hacc[0] = hacc[1] = 0.f;
    }
  }

  // gx running pointers: strides tloc 131072 | gate 32768 | wave 4096 |
  // j 2048 | mt 512 | gxlane 8   (gxlane = q4*16 + l15)
  const int gxlane = (q4 << 4) + l15;
  const char* pgx0 = (const char*)gxF + (size_t)(wave*4096 + mt*512 + gxlane*8);
  const char* pgx1 = pgx0 + 32768;
  const char* pgx2 = pgx0 + 65536;
  const char* pgx3 = pgx0 + 98304;
  #define GXP(g) ((g)==0 ? pgx0 : (g)==1 ? pgx1 : (g)==2 ? pgx2 : pgx3)

  // A-fragment from buffer cb: A-row = l15>>2 (real row r at A-rows 4r..4r+3)
  #define LD_A(cb, kc) (*reinterpret_cast<const bf16x8*>(&sH[(cb)*2048 + \
      (uint)((l15 >> 2)*512) + (((uint)((kc)*64 + lhi*16)) ^ ((uint)(l15 >> 2) << 5))]))
  // weight fragment (t, kc): regs or LDS, folded at compile time
  #define LD_W(t, kc) (((kc) >= 6 || ((kc) == 5 && (t) >= 6)) ? \
      *reinterpret_cast<const bf16x8*>(&sW[((wave*18 + \
        ((kc) == 6 ? (t) : (kc) == 7 ? (8 + (t)) : (16 + (t) - 6))) << 10) + lane*16]) \
      : wv[t][kc])

  // ---- prefetch gx for step 0 (gxb[t], t = g*2 + j; j at +2048 bytes) ----
  uint2 gxb[8];
  #pragma unroll
  for (int g = 0; g < 4; ++g) {
    gxb[2*g]     = *reinterpret_cast<const uint2*>(GXP(g));
    gxb[2*g + 1] = *reinterpret_cast<const uint2*>(GXP(g) + 2048);
  }

  // hs_out running pointer (L0): byte = tloc*32768 + (grp*4+lhi)*512 + u0*2
  char* hop = (char*)hs_out + (size_t)((grp*4 + lhi)*512 + (wave*32 + l15)*2);

  __syncthreads();

  int cur = 0;
  #pragma unroll 1
  for (int tloc = 0; tloc < CH; ++tloc) {
    // 1. acc init: reg-lhi of the gx uint2 -> all 4 C-in regs (only C-row
    //    4*lhi (reg 0) is consumed; rows 4b+1..3 are unused duplicates)
    f32x4 accA[4], accB[4];
    #pragma unroll
    for (int g = 0; g < 4; ++g) {
      float va = sel4(gxb[2*g],     lhi);
      float vb = sel4(gxb[2*g + 1], lhi);
      accA[g][0] = va; accA[g][1] = va; accA[g][2] = va; accA[g][3] = va;
      accB[g][0] = vb; accB[g][1] = vb; accB[g][2] = vb; accB[g][3] = vb;
    }
    // 2. advance pointers (+tloc stride), issue next step's gx loads
    pgx0 += 131072; pgx1 += 131072; pgx2 += 131072; pgx3 += 131072;
    #pragma unroll
    for (int g = 0; g < 4; ++g) {
      gxb[2*g]     = *reinterpret_cast<const uint2*>(GXP(g));
      gxb[2*g + 1] = *reinterpret_cast<const uint2*>(GXP(g) + 2048);
    }
    // 3. single kc-major MFMA block: 8 A-reads, 64 MFMAs
    #pragma unroll
    for (int kc = 0; kc < 8; ++kc) {
      bf16x8 a = LD_A(cur, kc);
      #pragma unroll
      for (int g = 0; g < 4; ++g) {
        accA[g] = __builtin_amdgcn_mfma_f32_16x16x32_bf16(a, LD_W(2*g,     kc), accA[g], 0, 0, 0);
        accB[g] = __builtin_amdgcn_mfma_f32_16x16x32_bf16(a, LD_W(2*g + 1, kc), accB[g], 0, 0, 0);
      }
    }
    // 4. j=0 activation (no repack: reg 0 = element (row lhi, unit w*32+l15))
    {
      float ig = sigm(accA[0][0]);
      float fg = sigm(accA[1][0]);
      float gg = tanhf_fast(accA[2][0]);
      float og = sigm(accA[3][0]);
      float cn = __builtin_fmaf(fg, c[0], ig * gg);
      c[0] = cn;
      float h = og * tanhf_fast(cn);
      if (!isL0) hacc[0] += h;
      const int u = wave*32 + l15;
      const uint wb = (uint)(lhi*512) + (((uint)(u*2)) ^ ((uint)lhi << 5));
      *reinterpret_cast<ushort*>(&sH[(cur ^ 1)*2048 + wb]) = f2b(h);
      if (isL0) *reinterpret_cast<ushort*>(hop) = f2b(h);
    }
    // 5. j=1 activation
    {
      float ig = sigm(accB[0][0]);
      float fg = sigm(accB[1][0]);
      float gg = tanhf_fast(accB[2][0]);
      float og = sigm(accB[3][0]);
      float cn = __builtin_fmaf(fg, c[1], ig * gg);
      c[1] = cn;
      float h = og * tanhf_fast(cn);
      if (!isL0) hacc[1] += h;
      const int u = wave*32 + 16 + l15;
      const uint wb = (uint)(lhi*512) + (((uint)(u*2)) ^ ((uint)lhi << 5));
      *reinterpret_cast<ushort*>(&sH[(cur ^ 1)*2048 + wb]) = f2b(h);
      if (isL0) *reinterpret_cast<ushort*>(hop + 32) = f2b(h);
    }
    if (isL0) hop += 32768;
    __syncthreads();
    cur ^= 1;
  }

  // ---- save state ----
  {
    uint* dst = reinterpret_cast<uint*>(h_state) + grp*512;
    const uint* src = reinterpret_cast<const uint*>(&sH[cur*2048]);
    if (tid < 512) dst[tid] = src[tid];
    float* cs = c_state + ((size_t)grp*512 + tid)*2;
    cs[0] = c[0]; cs[1] = c[1];
    if (!isL0) {
      float* ha = hacc_state + ((size_t)grp*512 + tid)*2;
      ha[0] = hacc[0]; ha[1] = hacc[1];
      #pragma unroll
      for (int j = 0; j < 2; ++j) {
        const int u = wave*32 + j*16 + l15;
        hsum_out[((size_t)grp*4 + lhi)*256 + u] = hacc[j];
      }
    }
  }
  #undef GXP
  #undef LD_A
  #undef LD_W
}

// ------------------------------- final fc ---------------------------------
__global__ void fc_kernel(const float* __restrict__ hsum, const float* __restrict__ Wfc,
                          const float* __restrict__ bfc, float* __restrict__ out)
{
  int tid = threadIdx.x;
  if (tid < 640) {
    int b = tid / 10, o = tid - b*10;
    const float* hp = hsum + b*256;
    const float* wp = Wfc + o*256;
    float s = 0.f;
    #pragma unroll 8
    for (int u = 0; u < 256; ++u) s = __builtin_fmaf(hp[u], wp[u], s);
    out[tid] = s * (1.f/1024.f) + bfc[o];
  }
}

extern "C" void kernel_launch(void* const* d_in, const int* in_sizes, int n_in,
                              void* d_out, int out_size, void* d_ws, size_t ws_size,
                              hipStream_t stream)
{
  const float* x    = (const float*)d_in[0];
  const float* Wih0 = (const float*)d_in[1];
  const float* Whh0 = (const float*)d_in[2];
  const float* bih0 = (const float*)d_in[3];
  const float* bhh0 = (const float*)d_in[4];
  const float* Wih1 = (const float*)d_in[5];
  const float* Whh1 = (const float*)d_in[6];
  const float* bih1 = (const float*)d_in[7];
  const float* bhh1 = (const float*)d_in[8];
  const float* Wfc  = (const float*)d_in[9];
  const float* bfc  = (const float*)d_in[10];
  float* out = (float*)d_out;
  char* ws = (char*)d_ws;

  // ws layout (total ~42.4 MB)
  ushort* Wb    = (ushort*)(ws);                               // 1,703,936 B
  float*  bsum  = (float*)(ws + 1703936);                      // 8 KB
  ushort* gxF0  = (ushort*)(ws + 2097152);                     // 16 MB
  ushort* gxF1  = (ushort*)(ws + 2097152 + 16777216);          // 16 MB
  ushort* hs0cA = (ushort*)(ws + 2097152 + 2*16777216);        // 4 MB
  ushort* hs0cB = (ushort*)(ws + 2097152 + 2*16777216 + 4194304);
  char*   st    = ws + 2097152 + 2*16777216 + 2*4194304;
  float*  hsum  = (float*)(st);                                // 64 KB
  ushort* hst0  = (ushort*)(st + 65536);                       // 32 KB
  ushort* hst1  = (ushort*)(st + 98304);                       // 32 KB
  float*  cst0  = (float*)(st + 131072);                       // 64 KB
  float*  cst1  = (float*)(st + 196608);                       // 64 KB
  float*  hast  = (float*)(st + 262144);                       // 64 KB

  hipLaunchKernelGGL(convert_weights, dim3(3328), dim3(256), 0, stream,
                     Wih0, Whh0, Wih1, Whh1, bih0, bhh0, bih1, bhh1, Wb, bsum);

  const ushort* Whh0b = Wb + 65536;
  const ushort* Wih1b = Wb + 327680;
  const ushort* Whh1b = Wb + 589824;

  ushort* hs0c[2] = { hs0cA, hs0cB };

  // pipeline fill: gemm0 chunk 0, then layer0 scan chunk 0
  hipLaunchKernelGGL(gemm_both, dim3(CH, 2), dim3(512), 0, stream,
                     (const void*)x, (const void*)hs0cA, Wb, Wih1b, bsum, bsum + 1024,
                     gxF0, gxF1, /*t0_g0=*/0, /*t0_g1=*/-1);
  hipLaunchKernelGGL(lstm_scan_fused, dim3(16), dim3(512), 0, stream,
                     gxF0, gxF1, Whh0b, Whh1b, hs0c[0], hsum,
                     hst0, hst1, cst0, cst1, hast, 0, 0, /*nL1=*/0);

  for (int c = 0; c < NCH; ++c) {
    const int nL0 = (c + 1 < NCH) ? 1 : 0;
    // merged: gemm1 chunk c (reads hs0c[c&1]) + gemm0 chunk c+1 (if any)
    hipLaunchKernelGGL(gemm_both, dim3(CH, 4), dim3(512), 0, stream,
                       (const void*)x, (const void*)hs0c[c & 1], Wb, Wih1b,
                       bsum, bsum + 1024, gxF0, gxF1,
                       nL0 ? (c + 1) * CH : -1, c * CH);
    hipLaunchKernelGGL(lstm_scan_fused, dim3(16 + 16*nL0), dim3(512), 0, stream,
                       gxF0, gxF1, Whh0b, Whh1b, hs0c[(c+1) & 1], hsum,
                       hst0, hst1, cst0, cst1, hast, (c+1)*CH, c*CH, /*nL1=*/1);
  }
  hipLaunchKernelGGL(fc_kernel, dim3(1), dim3(640), 0, stream, hsum, Wfc, bfc, out);
}

// Round 17
// 2344.146 us; speedup vs baseline: 1.9539x; 1.0215x over previous
//
#include <hip/hip_runtime.h>
#include <stdint.h>
#include <stddef.h>

// LSTM 2-layer, B=64,T=1024,D=64,H=256 -> fc(mean_t h)  [MI355X gfx950]
// R17 = R16 + scalar gx loads. After R16's row-placement trick each lane
// consumes ONLY bf16 reg `lhi` of its gx uint2 -> load exactly that ushort
// (pgx + lhi*2). Removes 8x sel4 (~24 VALU/step), halves gx fetch bytes,
// frees ~10 regs. Bit-identical numerics.
// Core (R16): real batch row b at MFMA A-rows 4b..4b+3 (LD_A row = l15>>2),
// so lane (lhi,l15) reg 0 = element (row lhi, unit) — no cross-lane repack.
// kc-major 64-MFMA block, 8 A-reads/step, sH dbuf 1 barrier/step,
// 16 WGs/layer x 4 rows, weights 46 frags regs + 18 LDS per wave, 512 thr,
// 2 waves/SIMD, merged gemm launch, fused scan0(c+1) || scan1(c).
// Measured balance (R16): step ~4530cy; MFMA ~43%, VALU ~41%, LDS ~56%.

#define T_LEN 1024
#define NB    64
#define DIN   64
#define HID   256
#define G4    1024
#define CH    128
#define NCH   (T_LEN/CH)

typedef __attribute__((ext_vector_type(8))) short  bf16x8;
typedef __attribute__((ext_vector_type(4))) float  f32x4;

__device__ __forceinline__ ushort f2b(float x) {      // fp32 -> bf16 RNE
  uint u = __float_as_uint(x);
  uint r = (u + 0x7fffu + ((u >> 16) & 1u)) >> 16;
  return (ushort)r;
}
__device__ __forceinline__ float sigm(float x) {
  float e = __expf(-x);
  return __builtin_amdgcn_rcpf(1.f + e);
}
__device__ __forceinline__ float tanhf_fast(float x) {
  x = fmaxf(-20.f, fminf(20.f, x));                   // exact for tanh, NaN-proof
  float e = __expf(-2.f * x);
  return (1.f - e) * __builtin_amdgcn_rcpf(1.f + e);
}

// ---------------- weight convert (fp32->bf16) + bias sums -----------------
__global__ void convert_weights(const float* __restrict__ Wih0, const float* __restrict__ Whh0,
                                const float* __restrict__ Wih1, const float* __restrict__ Whh1,
                                const float* __restrict__ bih0, const float* __restrict__ bhh0,
                                const float* __restrict__ bih1, const float* __restrict__ bhh1,
                                ushort* __restrict__ Wb, float* __restrict__ bsum)
{
  int i = blockIdx.x * 256 + threadIdx.x;
  const int n0 = G4*DIN, n1 = G4*HID;
  const int total = n0 + 3*n1;                 // 851968
  if (i < total) {
    float v;
    if (i < n0)           v = Wih0[i];
    else if (i < n0+n1)   v = Whh0[i-n0];
    else if (i < n0+2*n1) v = Wih1[i-n0-n1];
    else                  v = Whh1[i-n0-2*n1];
    Wb[i] = f2b(v);
  }
  if (i < G4)        bsum[i] = bih0[i] + bhh0[i];
  else if (i < 2*G4) bsum[i] = bih1[i-G4] + bhh1[i-G4];
}

// ------------- input-projection GEMM body: gx[t] = A_t @ W^T + bias --------
// SRC=0: A = x fp32 [B][T][DIN]  (KDIM=64)
// SRC=1: A = hs0 chunk bf16 [CH][64][HID] (KDIM=256)
// Output gxF bf16 in MFMA-fragment order: [tloc][ct 0..63][mt 0..3][lane][r]
template<int SRC, int KDIM>
__device__ __forceinline__ void gemm_body(
    char* sA, const void* __restrict__ Asrc, const ushort* __restrict__ W,
    const float* __restrict__ bias, ushort* __restrict__ gxF, int t0, int mt0)
{
  const int tid  = threadIdx.x;
  const int wave = tid >> 6, lane = tid & 63;
  const int l15 = lane & 15, lhi = lane >> 4;
  const int tloc = blockIdx.x;
  const int t = t0 + tloc;

  if (SRC == 0) {
    const float* x = (const float*)Asrc;
    int b = tid >> 3, k8 = (tid & 7) * 8;
    const float* xp = x + ((size_t)b * T_LEN + t) * DIN + k8;
    float4 v0 = *(const float4*)xp;
    float4 v1 = *(const float4*)(xp + 4);
    bf16x8 pv;
    pv[0]=(short)f2b(v0.x); pv[1]=(short)f2b(v0.y); pv[2]=(short)f2b(v0.z); pv[3]=(short)f2b(v0.w);
    pv[4]=(short)f2b(v1.x); pv[5]=(short)f2b(v1.y); pv[6]=(short)f2b(v1.z); pv[7]=(short)f2b(v1.w);
    uint bo = (uint)(b * KDIM * 2 + k8 * 2) ^ ((uint)(b & 7) << 4);
    *reinterpret_cast<bf16x8*>(&sA[bo]) = pv;
  } else {
    const ushort* hs = (const ushort*)Asrc;
    int b = tid >> 3, kb = tid & 7;
    #pragma unroll
    for (int j = 0; j < KDIM/64; ++j) {
      int k8 = (kb + j*8) * 8;
      bf16x8 v = *reinterpret_cast<const bf16x8*>(hs + ((size_t)tloc * 64 + b) * KDIM + k8);
      uint bo = (uint)(b * KDIM * 2 + k8 * 2) ^ ((uint)(b & 7) << 4);
      *reinterpret_cast<bf16x8*>(&sA[bo]) = v;
    }
  }
  __syncthreads();

  float bb[8];
  #pragma unroll
  for (int i = 0; i < 8; ++i) bb[i] = bias[(wave*8 + i)*16 + l15];

  f32x4 acc[2][8];
  #pragma unroll
  for (int m = 0; m < 2; ++m)
    #pragma unroll
    for (int i = 0; i < 8; ++i) {
      acc[m][i][0] = bb[i]; acc[m][i][1] = bb[i];
      acc[m][i][2] = bb[i]; acc[m][i][3] = bb[i];
    }

  #pragma unroll
  for (int kc = 0; kc < KDIM/32; ++kc) {
    const int koff = kc*32 + lhi*8;
    bf16x8 wf[8];
    #pragma unroll
    for (int i = 0; i < 8; ++i)
      wf[i] = *reinterpret_cast<const bf16x8*>(W + (size_t)((wave*8 + i)*16 + l15) * KDIM + koff);
    #pragma unroll
    for (int m = 0; m < 2; ++m) {
      const int row = (mt0 + m)*16 + l15;
      const uint bo = (uint)(row * KDIM * 2 + koff * 2) ^ ((uint)(row & 7) << 4);
      bf16x8 a = *reinterpret_cast<const bf16x8*>(&sA[bo]);
      #pragma unroll
      for (int i = 0; i < 8; ++i)
        acc[m][i] = __builtin_amdgcn_mfma_f32_16x16x32_bf16(a, wf[i], acc[m][i], 0, 0, 0);
    }
  }

  #pragma unroll
  for (int m = 0; m < 2; ++m)
    #pragma unroll
    for (int i = 0; i < 8; ++i) {
      const int ct = wave*8 + i;
      uint2 q;
      q.x = (uint)f2b(acc[m][i][0]) | ((uint)f2b(acc[m][i][1]) << 16);
      q.y = (uint)f2b(acc[m][i][2]) | ((uint)f2b(acc[m][i][3]) << 16);
      *reinterpret_cast<uint2*>(gxF + ((size_t)((tloc*64 + ct)*4 + (mt0+m))*64 + lane)*4) = q;
    }
}

// Merged gemm launch: grid (CH, 2..4). y 0,1 = gemm0 (x -> gx0, chunk t0_g0);
// y 2,3 = gemm1 (hs -> gx1, chunk t0_g1). Negative t0 disables a role.
__global__ __launch_bounds__(512) void gemm_both(
    const void* __restrict__ x, const void* __restrict__ hs,
    const ushort* __restrict__ W0, const ushort* __restrict__ W1,
    const float* __restrict__ b0, const float* __restrict__ b1,
    ushort* __restrict__ gx0, ushort* __restrict__ gx1,
    int t0_g0, int t0_g1)
{
  __shared__ __align__(16) char sA[64 * 256 * 2];
  if (blockIdx.y < 2) {
    if (t0_g0 < 0) return;
    gemm_body<0, 64>(sA, x, W0, b0, gx0, t0_g0, blockIdx.y * 2);
  } else {
    if (t0_g1 < 0) return;
    gemm_body<1, 256>(sA, hs, W1, b1, gx1, t0_g1, (blockIdx.y - 2) * 2);
  }
}

// --------------------------- fused recurrent scan --------------------------
// Blocks [0, 16*nL1): layer1 chunk t0_l1 (grp 0..15). Rest: layer0 t0_l0.
// Each grp owns batch rows [grp*4, grp*4+4), placed at MFMA A-rows 4b..4b+3
// (LD_A row = l15>>2). C/D row = lhi*4 + reg, so lane (lhi,l15) reg 0 holds
// element (row lhi, unit tile_col + l15) directly — no cross-lane repack.
// gx read: single ushort (reg lhi of the fragment uint2) at pgx + lhi*2.
// 512 thr, 8 waves, 2 waves/SIMD. Wave w owns units [32w,32w+32) x 4 gates
// = 8 tiles t = gate*2 + j. Frags/wave: 46 regs + 18 LDS. kc-major single
// MFMA block (8 A ds_reads, 64 MFMAs), then j0/j1 activation. 1 barrier/step.
__global__ __launch_bounds__(512)
__attribute__((amdgpu_waves_per_eu(2, 2)))
void lstm_scan_fused(
    const ushort* __restrict__ gxF0, const ushort* __restrict__ gxF1,
    const ushort* __restrict__ Whh0, const ushort* __restrict__ Whh1,
    ushort* __restrict__ hs_out,     // L0: chunk buffer [CH][64][256] bf16
    float* __restrict__ hsum_out,    // L1: [64][256]
    ushort* __restrict__ hst0, ushort* __restrict__ hst1,
    float* __restrict__ cst0, float* __restrict__ cst1,
    float* __restrict__ hacc_state,  // L1: [16][512][2]
    int t0_l0, int t0_l1, int nL1)
{
  __shared__ __align__(16) char sW[147456];   // [8 waves][18 frags][1024B]
  __shared__ __align__(16) char sH[4096];     // h double buffer, 2 x 2KB

  const int tid = threadIdx.x;
  const int wave = tid >> 6, lane = tid & 63;
  const int l15 = lane & 15, lhi = lane >> 4;
  const int isL0 = (blockIdx.x >= (uint)(16*nL1));
  const int grp  = blockIdx.x - (isL0 ? 16*nL1 : 0);  // 0..15
  const int mt   = grp >> 2;                          // gx M-tile
  const int q4   = grp & 3;                           // row quarter in tile

  const ushort* gxF     = isL0 ? gxF0 : gxF1;
  const ushort* Whh     = isL0 ? Whh0 : Whh1;
  ushort*       h_state = isL0 ? hst0 : hst1;
  float*        c_state = isL0 ? cst0 : cst1;
  const int     t0      = isL0 ? t0_l0 : t0_l1;

  // ---- load weights (once): 46 frags regs + 18 frags LDS per wave ----
  bf16x8 wv[8][6];                             // sparse: 46 live entries
  #pragma unroll
  for (int t = 0; t < 8; ++t) {
    const int g = t >> 1, j = t & 1;
    const ushort* wp = Whh + (size_t)(g*256 + wave*32 + j*16 + l15) * HID;
    #pragma unroll
    for (int kc = 0; kc < 8; ++kc) {
      bf16x8 w = *reinterpret_cast<const bf16x8*>(wp + kc*32 + lhi*8);
      if (kc >= 6 || (kc == 5 && t >= 6)) {
        const int fid = (kc == 6) ? t : (kc == 7) ? (8 + t) : (16 + (t - 6));
        *reinterpret_cast<bf16x8*>(&sW[((wave*18 + fid) << 10) + lane*16]) = w;
      } else {
        wv[t][kc] = w;
      }
    }
  }

  // ---- init / restore h into buffer 0 (2KB = 4 rows x 256 u, swizzled) ----
  if (t0 == 0) {
    reinterpret_cast<uint*>(sH)[tid] = 0u;
  } else {
    const uint* src = reinterpret_cast<const uint*>(h_state) + grp*512;
    reinterpret_cast<uint*>(sH)[tid] = src[tid];
  }

  float c[2], hacc[2];
  if (t0 == 0) {
    c[0] = c[1] = 0.f; hacc[0] = hacc[1] = 0.f;
  } else {
    const float* cs = c_state + ((size_t)grp*512 + tid)*2;
    c[0] = cs[0]; c[1] = cs[1];
    if (!isL0) {
      const float* ha = hacc_state + ((size_t)grp*512 + tid)*2;
      hacc[0] = ha[0]; hacc[1] = ha[1];
    } else {
      hacc[0] = hacc[1] = 0.f;
    }
  }

  // gx running pointers: strides tloc 131072 | gate 32768 | wave 4096 |
  // j 2048 | mt 512 | gxlane 8 | reg(lhi) 2   (gxlane = q4*16 + l15)
  const int gxlane = (q4 << 4) + l15;
  const char* pgx0 = (const char*)gxF + (size_t)(wave*4096 + mt*512 + gxlane*8 + lhi*2);
  const char* pgx1 = pgx0 + 32768;
  const char* pgx2 = pgx0 + 65536;
  const char* pgx3 = pgx0 + 98304;
  #define GXP(g) ((g)==0 ? pgx0 : (g)==1 ? pgx1 : (g)==2 ? pgx2 : pgx3)

  // A-fragment from buffer cb: A-row = l15>>2 (real row r at A-rows 4r..4r+3)
  #define LD_A(cb, kc) (*reinterpret_cast<const bf16x8*>(&sH[(cb)*2048 + \
      (uint)((l15 >> 2)*512) + (((uint)((kc)*64 + lhi*16)) ^ ((uint)(l15 >> 2) << 5))]))
  // weight fragment (t, kc): regs or LDS, folded at compile time
  #define LD_W(t, kc) (((kc) >= 6 || ((kc) == 5 && (t) >= 6)) ? \
      *reinterpret_cast<const bf16x8*>(&sW[((wave*18 + \
        ((kc) == 6 ? (t) : (kc) == 7 ? (8 + (t)) : (16 + (t) - 6))) << 10) + lane*16]) \
      : wv[t][kc])

  // ---- prefetch gx for step 0 (scalar ushort per tile; j at +2048) ----
  uint gxb[8];
  #pragma unroll
  for (int g = 0; g < 4; ++g) {
    gxb[2*g]     = *reinterpret_cast<const ushort*>(GXP(g));
    gxb[2*g + 1] = *reinterpret_cast<const ushort*>(GXP(g) + 2048);
  }

  // hs_out running pointer (L0): byte = tloc*32768 + (grp*4+lhi)*512 + u0*2
  char* hop = (char*)hs_out + (size_t)((grp*4 + lhi)*512 + (wave*32 + l15)*2);

  __syncthreads();

  int cur = 0;
  #pragma unroll 1
  for (int tloc = 0; tloc < CH; ++tloc) {
    // 1. acc init: gx value (bf16 -> fp32) broadcast to all 4 C regs
    //    (only C-row 4*lhi (reg 0) is consumed; others are unused dups)
    f32x4 accA[4], accB[4];
    #pragma unroll
    for (int g = 0; g < 4; ++g) {
      float va = __uint_as_float(gxb[2*g]     << 16);
      float vb = __uint_as_float(gxb[2*g + 1] << 16);
      accA[g][0] = va; accA[g][1] = va; accA[g][2] = va; accA[g][3] = va;
      accB[g][0] = vb; accB[g][1] = vb; accB[g][2] = vb; accB[g][3] = vb;
    }
    // 2. advance pointers (+tloc stride), issue next step's gx loads
    pgx0 += 131072; pgx1 += 131072; pgx2 += 131072; pgx3 += 131072;
    #pragma unroll
    for (int g = 0; g < 4; ++g) {
      gxb[2*g]     = *reinterpret_cast<const ushort*>(GXP(g));
      gxb[2*g + 1] = *reinterpret_cast<const ushort*>(GXP(g) + 2048);
    }
    // 3. single kc-major MFMA block: 8 A-reads, 64 MFMAs
    #pragma unroll
    for (int kc = 0; kc < 8; ++kc) {
      bf16x8 a = LD_A(cur, kc);
      #pragma unroll
      for (int g = 0; g < 4; ++g) {
        accA[g] = __builtin_amdgcn_mfma_f32_16x16x32_bf16(a, LD_W(2*g,     kc), accA[g], 0, 0, 0);
        accB[g] = __builtin_amdgcn_mfma_f32_16x16x32_bf16(a, LD_W(2*g + 1, kc), accB[g], 0, 0, 0);
      }
    }
    // 4. j=0 activation (no repack: reg 0 = element (row lhi, unit w*32+l15))
    {
      float ig = sigm(accA[0][0]);
      float fg = sigm(accA[1][0]);
      float gg = tanhf_fast(accA[2][0]);
      float og = sigm(accA[3][0]);
      float cn = __builtin_fmaf(fg, c[0], ig * gg);
      c[0] = cn;
      float h = og * tanhf_fast(cn);
      if (!isL0) hacc[0] += h;
      const int u = wave*32 + l15;
      const uint wb = (uint)(lhi*512) + (((uint)(u*2)) ^ ((uint)lhi << 5));
      *reinterpret_cast<ushort*>(&sH[(cur ^ 1)*2048 + wb]) = f2b(h);
      if (isL0) *reinterpret_cast<ushort*>(hop) = f2b(h);
    }
    // 5. j=1 activation
    {
      float ig = sigm(accB[0][0]);
      float fg = sigm(accB[1][0]);
      float gg = tanhf_fast(accB[2][0]);
      float og = sigm(accB[3][0]);
      float cn = __builtin_fmaf(fg, c[1], ig * gg);
      c[1] = cn;
      float h = og * tanhf_fast(cn);
      if (!isL0) hacc[1] += h;
      const int u = wave*32 + 16 + l15;
      const uint wb = (uint)(lhi*512) + (((uint)(u*2)) ^ ((uint)lhi << 5));
      *reinterpret_cast<ushort*>(&sH[(cur ^ 1)*2048 + wb]) = f2b(h);
      if (isL0) *reinterpret_cast<ushort*>(hop + 32) = f2b(h);
    }
    if (isL0) hop += 32768;
    __syncthreads();
    cur ^= 1;
  }

  // ---- save state ----
  {
    uint* dst = reinterpret_cast<uint*>(h_state) + grp*512;
    const uint* src = reinterpret_cast<const uint*>(&sH[cur*2048]);
    dst[tid] = src[tid];
    float* cs = c_state + ((size_t)grp*512 + tid)*2;
    cs[0] = c[0]; cs[1] = c[1];
    if (!isL0) {
      float* ha = hacc_state + ((size_t)grp*512 + tid)*2;
      ha[0] = hacc[0]; ha[1] = hacc[1];
      #pragma unroll
      for (int j = 0; j < 2; ++j) {
        const int u = wave*32 + j*16 + l15;
        hsum_out[((size_t)grp*4 + lhi)*256 + u] = hacc[j];
      }
    }
  }
  #undef GXP
  #undef LD_A
  #undef LD_W
}

// ------------------------------- final fc ---------------------------------
__global__ void fc_kernel(const float* __restrict__ hsum, const float* __restrict__ Wfc,
                          const float* __restrict__ bfc, float* __restrict__ out)
{
  int tid = threadIdx.x;
  if (tid < 640) {
    int b = tid / 10, o = tid - b*10;
    const float* hp = hsum + b*256;
    const float* wp = Wfc + o*256;
    float s = 0.f;
    #pragma unroll 8
    for (int u = 0; u < 256; ++u) s = __builtin_fmaf(hp[u], wp[u], s);
    out[tid] = s * (1.f/1024.f) + bfc[o];
  }
}

extern "C" void kernel_launch(void* const* d_in, const int* in_sizes, int n_in,
                              void* d_out, int out_size, void* d_ws, size_t ws_size,
                              hipStream_t stream)
{
  const float* x    = (const float*)d_in[0];
  const float* Wih0 = (const float*)d_in[1];
  const float* Whh0 = (const float*)d_in[2];
  const float* bih0 = (const float*)d_in[3];
  const float* bhh0 = (const float*)d_in[4];
  const float* Wih1 = (const float*)d_in[5];
  const float* Whh1 = (const float*)d_in[6];
  const float* bih1 = (const float*)d_in[7];
  const float* bhh1 = (const float*)d_in[8];
  const float* Wfc  = (const float*)d_in[9];
  const float* bfc  = (const float*)d_in[10];
  float* out = (float*)d_out;
  char* ws = (char*)d_ws;

  // ws layout (total ~42.4 MB)
  ushort* Wb    = (ushort*)(ws);                               // 1,703,936 B
  float*  bsum  = (float*)(ws + 1703936);                      // 8 KB
  ushort* gxF0  = (ushort*)(ws + 2097152);                     // 16 MB
  ushort* gxF1  = (ushort*)(ws + 2097152 + 16777216);          // 16 MB
  ushort* hs0cA = (ushort*)(ws + 2097152 + 2*16777216);        // 4 MB
  ushort* hs0cB = (ushort*)(ws + 2097152 + 2*16777216 + 4194304);
  char*   st    = ws + 2097152 + 2*16777216 + 2*4194304;
  float*  hsum  = (float*)(st);                                // 64 KB
  ushort* hst0  = (ushort*)(st + 65536);                       // 32 KB
  ushort* hst1  = (ushort*)(st + 98304);                       // 32 KB
  float*  cst0  = (float*)(st + 131072);                       // 64 KB
  float*  cst1  = (float*)(st + 196608);                       // 64 KB
  float*  hast  = (float*)(st + 262144);                       // 64 KB

  hipLaunchKernelGGL(convert_weights, dim3(3328), dim3(256), 0, stream,
                     Wih0, Whh0, Wih1, Whh1, bih0, bhh0, bih1, bhh1, Wb, bsum);

  const ushort* Whh0b = Wb + 65536;
  const ushort* Wih1b = Wb + 327680;
  const ushort* Whh1b = Wb + 589824;

  ushort* hs0c[2] = { hs0cA, hs0cB };

  // pipeline fill: gemm0 chunk 0, then layer0 scan chunk 0
  hipLaunchKernelGGL(gemm_both, dim3(CH, 2), dim3(512), 0, stream,
                     (const void*)x, (const void*)hs0cA, Wb, Wih1b, bsum, bsum + 1024,
                     gxF0, gxF1, /*t0_g0=*/0, /*t0_g1=*/-1);
  hipLaunchKernelGGL(lstm_scan_fused, dim3(16), dim3(512), 0, stream,
                     gxF0, gxF1, Whh0b, Whh1b, hs0c[0], hsum,
                     hst0, hst1, cst0, cst1, hast, 0, 0, /*nL1=*/0);

  for (int c = 0; c < NCH; ++c) {
    const int nL0 = (c + 1 < NCH) ? 1 : 0;
    // merged: gemm1 chunk c (reads hs0c[c&1]) + gemm0 chunk c+1 (if any)
    hipLaunchKernelGGL(gemm_both, dim3(CH, 4), dim3(512), 0, stream,
                       (const void*)x, (const void*)hs0c[c & 1], Wb, Wih1b,
                       bsum, bsum + 1024, gxF0, gxF1,
                       nL0 ? (c + 1) * CH : -1, c * CH);
    hipLaunchKernelGGL(lstm_scan_fused, dim3(16 + 16*nL0), dim3(512), 0, stream,
                       gxF0, gxF1, Whh0b, Whh1b, hs0c[(c+1) & 1], hsum,
                       hst0, hst1, cst0, cst1, hast, (c+1)*CH, c*CH, /*nL1=*/1);
  }
  hipLaunchKernelGGL(fc_kernel, dim3(1), dim3(640), 0, stream, hsum, Wfc, bfc, out);
}